// Round 11
// baseline (108.361 us; speedup 1.0000x reference)
//
#include <hip/hip_runtime.h>
#include <hip/hip_bf16.h>

#define HEADS 12
#define HD 64
#define DMODEL 768
#define TSEQ 2048
#define BATCH 2
#define NTOK (BATCH*TSEQ)   // 4096
#define NQKV (3*DMODEL)     // 2304
#define KSPLIT 4
#define BK 64
#define KVBLK 64

typedef __attribute__((ext_vector_type(8))) short bf16x8;
typedef __attribute__((ext_vector_type(4))) short bf16x4;
typedef __attribute__((ext_vector_type(4))) float f32x4;
typedef __attribute__((ext_vector_type(16))) float f32x16;

static __device__ inline float bf2f(short s) {
  union { float f; unsigned u; } cv; cv.u = ((unsigned)(unsigned short)s) << 16; return cv.f;
}
static __device__ inline short f2bf(float f) {
  union { float f; unsigned u; } cv; cv.f = f;
  unsigned u = cv.u;
  unsigned r = u + 0x7FFF + ((u >> 16) & 1);   // RNE
  return (short)(r >> 16);
}

// ---------------- conversion / packing (vectorized) ----------------
__global__ void cvt_kernel(const float* __restrict__ x,
                           const float* __restrict__ Wq, const float* __restrict__ Wk,
                           const float* __restrict__ Wv,
                           const float* __restrict__ bq, const float* __restrict__ bk,
                           const float* __restrict__ bv,
                           short* __restrict__ Xb, short* __restrict__ Wc,
                           float* __restrict__ bc) {
  const int NX4 = NTOK*DMODEL/4;          // 786432
  const int WSZ = DMODEL*DMODEL;          // 589824
  const int NW4 = 3*WSZ/4;                // 442368
  const int total = NX4 + NW4 + NQKV;
  for (int i = blockIdx.x*blockDim.x + threadIdx.x; i < total; i += gridDim.x*blockDim.x) {
    if (i < NX4) {
      f32x4 v = *(const f32x4*)&x[i*4];
      bf16x4 o;
      #pragma unroll
      for (int j=0;j<4;j++) o[j] = f2bf(v[j]);
      *(bf16x4*)&Xb[i*4] = o;
    } else if (i < NX4 + NW4) {
      int j = (i - NX4)*4;
      const float* src = (j < WSZ) ? &Wq[j] : (j < 2*WSZ) ? &Wk[j - WSZ] : &Wv[j - 2*WSZ];
      f32x4 v = *(const f32x4*)src;
      bf16x4 o;
      #pragma unroll
      for (int jj=0;jj<4;jj++) o[jj] = f2bf(v[jj]);
      *(bf16x4*)&Wc[j] = o;
    } else {
      int o = i - NX4 - NW4;
      bc[o] = (o < DMODEL) ? bq[o] : (o < 2*DMODEL) ? bk[o - DMODEL] : bv[o - 2*DMODEL];
    }
  }
}

// ---------------- fused QKV GEMM, m97-style: LDS dbuf + global_load_lds + swizzle ----------------
__global__ __launch_bounds__(256,2) void qkv_gemm(const short* __restrict__ Xb,
                                                  const short* __restrict__ Wc,
                                                  const float* __restrict__ bc,
                                                  short* __restrict__ Q, short* __restrict__ K,
                                                  short* __restrict__ V, short* __restrict__ Vt) {
  __shared__ __align__(16) char lds[65536];   // A0|B0|A1|B1 = 4 x 16KB
  const int nbn = NQKV/128;           // 18
  int swzb = ((blockIdx.x & 7) * 72) + (blockIdx.x >> 3);
  int bm = swzb / nbn, bn = swzb % nbn;
  int trow = bm*128, tcol = bn*128;
  int tid = threadIdx.x;
  int w = tid >> 6, l = tid & 63;
  int wr = w >> 1, wc = w & 1;
  int lr = l & 15, lg = l >> 4;

  int rbase = tid >> 3;
  int csw   = (tid & 7) ^ (rbase & 7);
  const short* pA = Xb + (size_t)(trow + rbase)*DMODEL + csw*8;
  const short* pB = Wc + (size_t)(tcol + rbase)*DMODEL + csw*8;

  unsigned aoff[4][2], boff[4][2];
  #pragma unroll
  for (int m=0;m<4;m++)
    #pragma unroll
    for (int kc2=0;kc2<2;kc2++) {
      int rowa = wr*64 + m*16 + lr;
      aoff[m][kc2] = rowa*128 + (((kc2*4+lg) ^ (rowa&7))*16);
      int rowb = wc*64 + m*16 + lr;
      boff[m][kc2] = rowb*128 + (((kc2*4+lg) ^ (rowb&7))*16);
    }

  f32x4 acc[4][4];
  #pragma unroll
  for (int m=0;m<4;m++)
    #pragma unroll
    for (int n=0;n<4;n++) acc[m][n] = (f32x4)0.f;

  auto stage = [&](int buf, int ks) {
    int k0 = ks*BK;
    unsigned base = (unsigned)buf*32768u;
    #pragma unroll
    for (int i=0;i<4;i++) {
      __builtin_amdgcn_global_load_lds(
        (const __attribute__((address_space(1))) unsigned int*)(pA + k0 + i*(32*DMODEL)),
        (__attribute__((address_space(3))) unsigned int*)(lds + base + (i*256 + w*64)*16),
        16, 0, 0);
      __builtin_amdgcn_global_load_lds(
        (const __attribute__((address_space(1))) unsigned int*)(pB + k0 + i*(32*DMODEL)),
        (__attribute__((address_space(3))) unsigned int*)(lds + base + 16384 + (i*256 + w*64)*16),
        16, 0, 0);
    }
  };

  stage(0, 0);
  asm volatile("s_waitcnt vmcnt(0)");
  __syncthreads();

  const int NKS = DMODEL/BK;   // 12
  for (int ks = 0; ks < NKS; ks++) {
    int cur = ks & 1;
    if (ks + 1 < NKS) stage(cur ^ 1, ks + 1);
    unsigned abase = (unsigned)cur*32768u, bbase = abase + 16384u;
    bf16x8 af[4][2], bfr[4][2];
    #pragma unroll
    for (int m=0;m<4;m++)
      #pragma unroll
      for (int kc2=0;kc2<2;kc2++) {
        af[m][kc2]  = *(const bf16x8*)(lds + abase + aoff[m][kc2]);
        bfr[m][kc2] = *(const bf16x8*)(lds + bbase + boff[m][kc2]);
      }
    __builtin_amdgcn_s_setprio(1);
    #pragma unroll
    for (int m=0;m<4;m++)
      #pragma unroll
      for (int n=0;n<4;n++)
        #pragma unroll
        for (int kc2=0;kc2<2;kc2++)
          acc[m][n] = __builtin_amdgcn_mfma_f32_16x16x32_bf16(af[m][kc2], bfr[n][kc2], acc[m][n], 0, 0, 0);
    __builtin_amdgcn_s_setprio(0);
    __syncthreads();
  }

  // ---- epilogue: stage 128x128 bf16 tile in LDS, coalesced stores ----
  short* ltile = (short*)lds;
  float bcv[4];
  #pragma unroll
  for (int n=0;n<4;n++) bcv[n] = bc[tcol + wc*64 + n*16 + lr];
  #pragma unroll
  for (int m=0;m<4;m++)
    #pragma unroll
    for (int n=0;n<4;n++)
      #pragma unroll
      for (int j=0;j<4;j++)
        ltile[(wr*64 + m*16 + lg*4 + j)*128 + wc*64 + n*16 + lr] = f2bf(acc[m][n][j] + bcv[n]);
  __syncthreads();

  int sel = tcol / DMODEL;            // 0=Q 1=K 2=V
  int h0  = (tcol % DMODEL) >> 6;
  short* dstQKV = (sel == 0) ? Q : (sel == 1) ? K : V;
  #pragma unroll
  for (int rr=0; rr<8; rr++) {
    int idx = rr*256 + tid;
    int r2 = idx >> 4, c2 = idx & 15;
    int t = trow + r2;
    int b = t >> 11, tt = t & (TSEQ-1);
    int hh = h0 + (c2 >> 3), d0 = (c2 & 7)*8;
    bf16x8 val = *(const bf16x8*)&ltile[r2*128 + c2*8];
    *(bf16x8*)&dstQKV[((size_t)(b*HEADS + hh)*TSEQ + tt)*HD + d0] = val;
  }
  if (sel == 2) {
    #pragma unroll
    for (int rr=0; rr<8; rr++) {
      int idx = rr*256 + tid;
      int col = idx >> 4, tc8 = idx & 15;
      int hh = h0 + (col >> 6), d = col & 63;
      int t0 = trow + tc8*8;
      int b = t0 >> 11, tt0 = t0 & (TSEQ-1);
      bf16x8 v;
      #pragma unroll
      for (int j=0;j<8;j++) v[j] = ltile[(tc8*8 + j)*128 + col];
      *(bf16x8*)&Vt[((size_t)(b*HEADS + hh)*HD + d)*TSEQ + tt0] = v;
    }
  }
}

// ---------------- per-(b,h,d) column sum of V — two-stage ----------------
__global__ __launch_bounds__(256) void vsum1(const short* __restrict__ V, float* __restrict__ part) {
  int bh = blockIdx.x >> 3, tc = blockIdx.x & 7;   // grid 24*8
  int d = threadIdx.x & 63, tg = threadIdx.x >> 6;
  const short* p = V + ((size_t)bh*TSEQ + tc*256)*HD + d;
  float s = 0.f;
  #pragma unroll 8
  for (int i = 0; i < 64; i++) s += bf2f(p[(size_t)(tg + i*4)*HD]);
  __shared__ float red[4][64];
  red[tg][d] = s;
  __syncthreads();
  if (tg == 0) part[(bh*8 + tc)*64 + d] = red[0][d] + red[1][d] + red[2][d] + red[3][d];
}
__global__ void vsum2(const float* __restrict__ part, float* __restrict__ vs) {
  int bh = blockIdx.x, d = threadIdx.x;  // 24 x 64
  float s = 0.f;
  for (int c = 0; c < 8; c++) s += part[(bh*8 + c)*64 + d];
  vs[bh*64 + d] = s;
}

// ---------------- flash attention: 32x32 MFMA, LDS-staged K/Vt (swizzled), static max ----------------
__global__ __launch_bounds__(256,3) void attn_kernel(
    const short* __restrict__ Q, const short* __restrict__ K,
    const short* __restrict__ Vt,
    short* __restrict__ po, float* __restrict__ pml) {
  const int nqt = TSEQ/128;            // 16
  int bid = blockIdx.x;
  int ks_id = bid % KSPLIT;
  int r = bid / KSPLIT;
  int qt = r % nqt;
  int bh = r / nqt;

  int tid = threadIdx.x;
  int w = tid >> 6, lane = tid & 63;
  int q5 = lane & 31, hi = lane >> 5;
  int qrow = qt*128 + w*32 + q5;

  // double-buffered K and Vt tiles: 64 rows x 128B each, XOR-swizzled 16B chunks
  __shared__ __align__(16) char kbuf[2][8192];
  __shared__ __align__(16) char vbuf[2][8192];

  const short* Qp  = Q  + (size_t)bh*TSEQ*HD;
  const short* Kp  = K  + (size_t)bh*TSEQ*HD;
  const short* Vtp = Vt + (size_t)bh*HD*TSEQ;

  bf16x8 qf[4];
  #pragma unroll
  for (int c=0;c<4;c++)
    qf[c] = *(const bf16x8*)&Qp[(size_t)qrow*HD + c*16 + hi*8];

  const int ksoff = ks_id*(TSEQ/KSPLIT);   // 512-key slice

  auto stage = [&](int buf, int kt) {
    int kb = ksoff + kt*KVBLK;
    #pragma unroll
    for (int i=0;i<2;i++) {
      int l0 = i*256 + w*64;
      int l  = l0 + lane;
      int rr = l >> 3, cc = l & 7;
      int sk = cc ^ (rr & 7);
      __builtin_amdgcn_global_load_lds(
        (const __attribute__((address_space(1))) unsigned int*)(Kp + (size_t)(kb + rr)*HD + sk*8),
        (__attribute__((address_space(3))) unsigned int*)(kbuf[buf] + l0*16),
        16, 0, 0);
      __builtin_amdgcn_global_load_lds(
        (const __attribute__((address_space(1))) unsigned int*)(Vtp + (size_t)rr*TSEQ + kb + sk*8),
        (__attribute__((address_space(3))) unsigned int*)(vbuf[buf] + l0*16),
        16, 0, 0);
    }
  };

  f32x16 o0 = (f32x16)0.f, o1 = (f32x16)0.f;
  float psum0 = 0.f, psum1 = 0.f;
  // exp(s*scale - 8) == exp2(s*c1 - c2): one v_fma + one v_exp
  const float c1 = 0.125f * 1.44269504f;
  const float c2 = 8.f * 1.44269504f;
  const int rx = q5 & 7;        // row-XOR class for this lane's fragment rows

  stage(0, 0);
  asm volatile("s_waitcnt vmcnt(0)");
  __syncthreads();

  const int NT = TSEQ/KSPLIT/KVBLK;   // 8
  for (int kt = 0; kt < NT; kt++) {
    int cur = kt & 1;
    if (kt + 1 < NT) stage(cur ^ 1, kt + 1);

    // hoist all K fragment ds_reads: subtile-1 latency hides under subtile-0 compute
    bf16x8 kf[2][4];
    #pragma unroll
    for (int t=0;t<2;t++)
      #pragma unroll
      for (int c=0;c<4;c++)
        kf[t][c] = *(const bf16x8*)(kbuf[cur] + (t*32+q5)*128 + (((c*2+hi) ^ rx)*16));

    #pragma unroll
    for (int t=0;t<2;t++) {
      f32x16 st = (f32x16)0.f;
      __builtin_amdgcn_s_setprio(1);
      #pragma unroll
      for (int c=0;c<4;c++)
        st = __builtin_amdgcn_mfma_f32_32x32x16_bf16(kf[t][c], qf[c], st, 0, 0, 0);
      __builtin_amdgcn_s_setprio(0);

      // Vt fragments: rows q5 (o0) and q5+32 (o1), key-chunk = t*4+ks2*2+hi
      bf16x8 vf0[2], vf1[2];
      #pragma unroll
      for (int ks2=0;ks2<2;ks2++) {
        int kc = ((t*4 + ks2*2 + hi) ^ rx)*16;
        vf0[ks2] = *(const bf16x8*)(vbuf[cur] + q5*128 + kc);
        vf1[ks2] = *(const bf16x8*)(vbuf[cur] + (q5+32)*128 + kc);
      }

      #pragma unroll
      for (int i=0;i<16;i+=2) {
        st[i]   = exp2f(st[i]*c1   - c2);
        st[i+1] = exp2f(st[i+1]*c1 - c2);
        psum0 += st[i];
        psum1 += st[i+1];
      }
      unsigned pw[4][2];
      #pragma unroll
      for (int a=0;a<4;a++)
        #pragma unroll
        for (int p=0;p<2;p++) {
          union { __hip_bfloat162 h; unsigned u; } cvp;
          cvp.h = __float22bfloat162_rn(float2{st[a*4+2*p], st[a*4+2*p+1]});
          pw[a][p] = cvp.u;
        }
      #pragma unroll
      for (int ks2=0;ks2<2;ks2++) {
        unsigned self0 = hi ? pw[2*ks2+1][0] : pw[2*ks2][0];
        unsigned self1 = hi ? pw[2*ks2+1][1] : pw[2*ks2][1];
        unsigned send0 = hi ? pw[2*ks2][0]   : pw[2*ks2+1][0];
        unsigned send1 = hi ? pw[2*ks2][1]   : pw[2*ks2+1][1];
        unsigned recv0 = (unsigned)__shfl_xor((int)send0, 32);
        unsigned recv1 = (unsigned)__shfl_xor((int)send1, 32);
        union { unsigned u[4]; bf16x8 v; } bw;
        bw.u[0] = hi ? recv0 : self0;
        bw.u[1] = hi ? recv1 : self1;
        bw.u[2] = hi ? self0 : recv0;
        bw.u[3] = hi ? self1 : recv1;
        __builtin_amdgcn_s_setprio(1);
        o0 = __builtin_amdgcn_mfma_f32_32x32x16_bf16(vf0[ks2], bw.v, o0, 0, 0, 0);
        o1 = __builtin_amdgcn_mfma_f32_32x32x16_bf16(vf1[ks2], bw.v, o1, 0, 0, 0);
        __builtin_amdgcn_s_setprio(0);
      }
    }

    asm volatile("s_waitcnt vmcnt(0)");
    __syncthreads();
  }

  float psum = psum0 + psum1;
  float ltot = psum + __shfl_xor(psum, 32);
  size_t gq = (size_t)bh*TSEQ + qrow;
  if (!hi) pml[gq*KSPLIT + ks_id] = ltot;

  #pragma unroll
  for (int rg=0; rg<4; rg++) {
    bf16x4 pk0, pk1;
    #pragma unroll
    for (int rj=0;rj<4;rj++) { pk0[rj] = f2bf(o0[rg*4+rj]); pk1[rj] = f2bf(o1[rg*4+rj]); }
    int d0 = rg*8 + hi*4;
    *(bf16x4*)&po[(gq*KSPLIT + ks_id)*HD + d0]      = pk0;
    *(bf16x4*)&po[(gq*KSPLIT + ks_id)*HD + 32 + d0] = pk1;
  }
}

// ---------------- combine split-K partials + shaped epilogue ----------------
__global__ __launch_bounds__(256) void combine_kernel(
    const short* __restrict__ po, const float* __restrict__ pml,
    const short* __restrict__ V, const float* __restrict__ vs,
    const float* __restrict__ alpha, const float* __restrict__ beta,
    const float* __restrict__ gamma, const float* __restrict__ Cc,
    float* __restrict__ out) {
  size_t gq = (size_t)blockIdx.x*4 + (threadIdx.x >> 6);
  int d = threadIdx.x & 63;
  int bh = (int)(gq >> 11), q = (int)(gq & (TSEQ-1));
  int b = bh / HEADS, h = bh % HEADS;

  float L = 0.f, acc = 0.f;
  #pragma unroll
  for (int i=0;i<KSPLIT;i++) {
    L   += pml[gq*KSPLIT + i];
    acc += bf2f(po[(gq*KSPLIT + i)*HD + d]);
  }
  float sv = acc / L;
  float al = alpha[h], be = beta[h], ga = gamma[h], cc = Cc[h];
  float vv = bf2f(V[((size_t)bh*TSEQ + q)*HD + d]);
  out[((size_t)b*TSEQ + q)*DMODEL + h*HD + d] = al*vv + be*sv - ga*cc*vs[bh*HD + d];
}

extern "C" void kernel_launch(void* const* d_in, const int* in_sizes, int n_in,
                              void* d_out, int out_size, void* d_ws, size_t ws_size,
                              hipStream_t stream) {
  const float* x     = (const float*)d_in[0];
  const float* Wq    = (const float*)d_in[1];
  const float* bq    = (const float*)d_in[2];
  const float* Wk    = (const float*)d_in[3];
  const float* bk    = (const float*)d_in[4];
  const float* Wv    = (const float*)d_in[5];
  const float* bv    = (const float*)d_in[6];
  const float* alpha = (const float*)d_in[7];
  const float* beta  = (const float*)d_in[8];
  const float* gamma = (const float*)d_in[9];
  const float* Cc    = (const float*)d_in[10];
  float* out = (float*)d_out;

  char* ws = (char*)d_ws;
  size_t off = 0;
  auto alloc = [&](size_t bytes) -> void* {
    void* p = ws + off; off += (bytes + 255) & ~(size_t)255; return p;
  };
  short* Xb = (short*)alloc((size_t)NTOK*DMODEL*2);
  short* Wc = (short*)alloc((size_t)NQKV*DMODEL*2);
  float* bc = (float*)alloc((size_t)NQKV*4);
  short* Q  = (short*)alloc((size_t)BATCH*HEADS*TSEQ*HD*2);
  short* K  = (short*)alloc((size_t)BATCH*HEADS*TSEQ*HD*2);
  short* V  = (short*)alloc((size_t)BATCH*HEADS*TSEQ*HD*2);
  short* Vt = (short*)alloc((size_t)BATCH*HEADS*TSEQ*HD*2);
  float* vs = (float*)alloc((size_t)BATCH*HEADS*HD*4);
  float* part = (float*)alloc((size_t)BATCH*HEADS*8*HD*4);
  short* po  = (short*)alloc((size_t)BATCH*HEADS*TSEQ*KSPLIT*HD*2);   // 25.2 MB
  float* pml = (float*)alloc((size_t)BATCH*HEADS*TSEQ*KSPLIT*4);      // 0.8 MB

  cvt_kernel<<<1024, 256, 0, stream>>>(x, Wq, Wk, Wv, bq, bk, bv, Xb, Wc, bc);
  qkv_gemm<<<(NTOK/128)*(NQKV/128), 256, 0, stream>>>(Xb, Wc, bc, Q, K, V, Vt);
  vsum1<<<BATCH*HEADS*8, 256, 0, stream>>>(V, part);
  vsum2<<<BATCH*HEADS, 64, 0, stream>>>(part, vs);
  attn_kernel<<<BATCH*HEADS*(TSEQ/128)*KSPLIT, 256, 0, stream>>>(Q, K, Vt, po, pml);
  combine_kernel<<<BATCH*HEADS*TSEQ/4, 256, 0, stream>>>(po, pml, V, vs, alpha, beta, gamma, Cc, out);
}

// Round 12
// 96.090 us; speedup vs baseline: 1.1277x; 1.1277x over previous
//
#include <hip/hip_runtime.h>
#include <hip/hip_bf16.h>

#define HEADS 12
#define HD 64
#define DMODEL 768
#define TSEQ 2048
#define BATCH 2
#define NTOK (BATCH*TSEQ)   // 4096
#define NQKV (3*DMODEL)     // 2304
#define KSPLIT 4
#define BK 64
#define KVBLK 64

typedef __attribute__((ext_vector_type(8))) short bf16x8;
typedef __attribute__((ext_vector_type(4))) short bf16x4;
typedef __attribute__((ext_vector_type(4))) float f32x4;
typedef __attribute__((ext_vector_type(16))) float f32x16;
typedef __attribute__((ext_vector_type(2))) unsigned uint32x2;

static __device__ inline float bf2f(short s) {
  union { float f; unsigned u; } cv; cv.u = ((unsigned)(unsigned short)s) << 16; return cv.f;
}
static __device__ inline short f2bf(float f) {
  union { float f; unsigned u; } cv; cv.f = f;
  unsigned u = cv.u;
  unsigned r = u + 0x7FFF + ((u >> 16) & 1);   // RNE
  return (short)(r >> 16);
}

// ---------------- conversion / packing (vectorized) ----------------
__global__ void cvt_kernel(const float* __restrict__ x,
                           const float* __restrict__ Wq, const float* __restrict__ Wk,
                           const float* __restrict__ Wv,
                           const float* __restrict__ bq, const float* __restrict__ bk,
                           const float* __restrict__ bv,
                           short* __restrict__ Xb, short* __restrict__ Wc,
                           float* __restrict__ bc) {
  const int NX4 = NTOK*DMODEL/4;          // 786432
  const int WSZ = DMODEL*DMODEL;          // 589824
  const int NW4 = 3*WSZ/4;                // 442368
  const int total = NX4 + NW4 + NQKV;
  for (int i = blockIdx.x*blockDim.x + threadIdx.x; i < total; i += gridDim.x*blockDim.x) {
    if (i < NX4) {
      f32x4 v = *(const f32x4*)&x[i*4];
      bf16x4 o;
      #pragma unroll
      for (int j=0;j<4;j++) o[j] = f2bf(v[j]);
      *(bf16x4*)&Xb[i*4] = o;
    } else if (i < NX4 + NW4) {
      int j = (i - NX4)*4;
      const float* src = (j < WSZ) ? &Wq[j] : (j < 2*WSZ) ? &Wk[j - WSZ] : &Wv[j - 2*WSZ];
      f32x4 v = *(const f32x4*)src;
      bf16x4 o;
      #pragma unroll
      for (int jj=0;jj<4;jj++) o[jj] = f2bf(v[jj]);
      *(bf16x4*)&Wc[j] = o;
    } else {
      int o = i - NX4 - NW4;
      bc[o] = (o < DMODEL) ? bq[o] : (o < 2*DMODEL) ? bk[o - DMODEL] : bv[o - 2*DMODEL];
    }
  }
}

// ---------------- fused QKV GEMM, m97-style: LDS dbuf + global_load_lds + swizzle ----------------
__global__ __launch_bounds__(256,2) void qkv_gemm(const short* __restrict__ Xb,
                                                  const short* __restrict__ Wc,
                                                  const float* __restrict__ bc,
                                                  short* __restrict__ Q, short* __restrict__ K,
                                                  short* __restrict__ V, short* __restrict__ Vt) {
  __shared__ __align__(16) char lds[65536];   // A0|B0|A1|B1 = 4 x 16KB
  const int nbn = NQKV/128;           // 18
  int swzb = ((blockIdx.x & 7) * 72) + (blockIdx.x >> 3);
  int bm = swzb / nbn, bn = swzb % nbn;
  int trow = bm*128, tcol = bn*128;
  int tid = threadIdx.x;
  int w = tid >> 6, l = tid & 63;
  int wr = w >> 1, wc = w & 1;
  int lr = l & 15, lg = l >> 4;

  int rbase = tid >> 3;
  int csw   = (tid & 7) ^ (rbase & 7);
  const short* pA = Xb + (size_t)(trow + rbase)*DMODEL + csw*8;
  const short* pB = Wc + (size_t)(tcol + rbase)*DMODEL + csw*8;

  unsigned aoff[4][2], boff[4][2];
  #pragma unroll
  for (int m=0;m<4;m++)
    #pragma unroll
    for (int kc2=0;kc2<2;kc2++) {
      int rowa = wr*64 + m*16 + lr;
      aoff[m][kc2] = rowa*128 + (((kc2*4+lg) ^ (rowa&7))*16);
      int rowb = wc*64 + m*16 + lr;
      boff[m][kc2] = rowb*128 + (((kc2*4+lg) ^ (rowb&7))*16);
    }

  f32x4 acc[4][4];
  #pragma unroll
  for (int m=0;m<4;m++)
    #pragma unroll
    for (int n=0;n<4;n++) acc[m][n] = (f32x4)0.f;

  auto stage = [&](int buf, int ks) {
    int k0 = ks*BK;
    unsigned base = (unsigned)buf*32768u;
    #pragma unroll
    for (int i=0;i<4;i++) {
      __builtin_amdgcn_global_load_lds(
        (const __attribute__((address_space(1))) unsigned int*)(pA + k0 + i*(32*DMODEL)),
        (__attribute__((address_space(3))) unsigned int*)(lds + base + (i*256 + w*64)*16),
        16, 0, 0);
      __builtin_amdgcn_global_load_lds(
        (const __attribute__((address_space(1))) unsigned int*)(pB + k0 + i*(32*DMODEL)),
        (__attribute__((address_space(3))) unsigned int*)(lds + base + 16384 + (i*256 + w*64)*16),
        16, 0, 0);
    }
  };

  stage(0, 0);
  asm volatile("s_waitcnt vmcnt(0)");
  __syncthreads();

  const int NKS = DMODEL/BK;   // 12
  for (int ks = 0; ks < NKS; ks++) {
    int cur = ks & 1;
    if (ks + 1 < NKS) stage(cur ^ 1, ks + 1);
    unsigned abase = (unsigned)cur*32768u, bbase = abase + 16384u;
    bf16x8 af[4][2], bfr[4][2];
    #pragma unroll
    for (int m=0;m<4;m++)
      #pragma unroll
      for (int kc2=0;kc2<2;kc2++) {
        af[m][kc2]  = *(const bf16x8*)(lds + abase + aoff[m][kc2]);
        bfr[m][kc2] = *(const bf16x8*)(lds + bbase + boff[m][kc2]);
      }
    __builtin_amdgcn_s_setprio(1);
    #pragma unroll
    for (int m=0;m<4;m++)
      #pragma unroll
      for (int n=0;n<4;n++)
        #pragma unroll
        for (int kc2=0;kc2<2;kc2++)
          acc[m][n] = __builtin_amdgcn_mfma_f32_16x16x32_bf16(af[m][kc2], bfr[n][kc2], acc[m][n], 0, 0, 0);
    __builtin_amdgcn_s_setprio(0);
    __syncthreads();
  }

  // ---- epilogue: stage 128x128 bf16 tile in LDS, coalesced stores ----
  short* ltile = (short*)lds;
  float bcv[4];
  #pragma unroll
  for (int n=0;n<4;n++) bcv[n] = bc[tcol + wc*64 + n*16 + lr];
  #pragma unroll
  for (int m=0;m<4;m++)
    #pragma unroll
    for (int n=0;n<4;n++)
      #pragma unroll
      for (int j=0;j<4;j++)
        ltile[(wr*64 + m*16 + lg*4 + j)*128 + wc*64 + n*16 + lr] = f2bf(acc[m][n][j] + bcv[n]);
  __syncthreads();

  int sel = tcol / DMODEL;            // 0=Q 1=K 2=V
  int h0  = (tcol % DMODEL) >> 6;
  short* dstQKV = (sel == 0) ? Q : (sel == 1) ? K : V;
  #pragma unroll
  for (int rr=0; rr<8; rr++) {
    int idx = rr*256 + tid;
    int r2 = idx >> 4, c2 = idx & 15;
    int t = trow + r2;
    int b = t >> 11, tt = t & (TSEQ-1);
    int hh = h0 + (c2 >> 3), d0 = (c2 & 7)*8;
    bf16x8 val = *(const bf16x8*)&ltile[r2*128 + c2*8];
    *(bf16x8*)&dstQKV[((size_t)(b*HEADS + hh)*TSEQ + tt)*HD + d0] = val;
  }
  if (sel == 2) {
    #pragma unroll
    for (int rr=0; rr<8; rr++) {
      int idx = rr*256 + tid;
      int col = idx >> 4, tc8 = idx & 15;
      int hh = h0 + (col >> 6), d = col & 63;
      int t0 = trow + tc8*8;
      int b = t0 >> 11, tt0 = t0 & (TSEQ-1);
      bf16x8 v;
      #pragma unroll
      for (int j=0;j<8;j++) v[j] = ltile[(tc8*8 + j)*128 + col];
      *(bf16x8*)&Vt[((size_t)(b*HEADS + hh)*HD + d)*TSEQ + tt0] = v;
    }
  }
}

// ---------------- per-(b,h,d) column sum of V — two-stage ----------------
__global__ __launch_bounds__(256) void vsum1(const short* __restrict__ V, float* __restrict__ part) {
  int bh = blockIdx.x >> 3, tc = blockIdx.x & 7;   // grid 24*8
  int d = threadIdx.x & 63, tg = threadIdx.x >> 6;
  const short* p = V + ((size_t)bh*TSEQ + tc*256)*HD + d;
  float s = 0.f;
  #pragma unroll 8
  for (int i = 0; i < 64; i++) s += bf2f(p[(size_t)(tg + i*4)*HD]);
  __shared__ float red[4][64];
  red[tg][d] = s;
  __syncthreads();
  if (tg == 0) part[(bh*8 + tc)*64 + d] = red[0][d] + red[1][d] + red[2][d] + red[3][d];
}
__global__ void vsum2(const float* __restrict__ part, float* __restrict__ vs) {
  int bh = blockIdx.x, d = threadIdx.x;  // 24 x 64
  float s = 0.f;
  for (int c = 0; c < 8; c++) s += part[(bh*8 + c)*64 + d];
  vs[bh*64 + d] = s;
}

// ---------------- flash attention: 32x32 MFMA, LDS-staged K/Vt (swizzled), static max ----------------
__global__ __launch_bounds__(256,3) void attn_kernel(
    const short* __restrict__ Q, const short* __restrict__ K,
    const short* __restrict__ Vt,
    short* __restrict__ po, float* __restrict__ pml) {
  const int nqt = TSEQ/128;            // 16
  int bid = blockIdx.x;
  int ks_id = bid % KSPLIT;
  int r = bid / KSPLIT;
  int qt = r % nqt;
  int bh = r / nqt;

  int tid = threadIdx.x;
  int w = tid >> 6, lane = tid & 63;
  int q5 = lane & 31, hi = lane >> 5;
  int qrow = qt*128 + w*32 + q5;

  // double-buffered K and Vt tiles: 64 rows x 128B each, XOR-swizzled 16B chunks
  __shared__ __align__(16) char kbuf[2][8192];
  __shared__ __align__(16) char vbuf[2][8192];

  const short* Qp  = Q  + (size_t)bh*TSEQ*HD;
  const short* Kp  = K  + (size_t)bh*TSEQ*HD;
  const short* Vtp = Vt + (size_t)bh*HD*TSEQ;

  bf16x8 qf[4];
  #pragma unroll
  for (int c=0;c<4;c++)
    qf[c] = *(const bf16x8*)&Qp[(size_t)qrow*HD + c*16 + hi*8];

  const int ksoff = ks_id*(TSEQ/KSPLIT);   // 512-key slice

  auto stage = [&](int buf, int kt) {
    int kb = ksoff + kt*KVBLK;
    #pragma unroll
    for (int i=0;i<2;i++) {
      int l0 = i*256 + w*64;
      int l  = l0 + lane;
      int rr = l >> 3, cc = l & 7;
      int sk = cc ^ (rr & 7);
      __builtin_amdgcn_global_load_lds(
        (const __attribute__((address_space(1))) unsigned int*)(Kp + (size_t)(kb + rr)*HD + sk*8),
        (__attribute__((address_space(3))) unsigned int*)(kbuf[buf] + l0*16),
        16, 0, 0);
      __builtin_amdgcn_global_load_lds(
        (const __attribute__((address_space(1))) unsigned int*)(Vtp + (size_t)rr*TSEQ + kb + sk*8),
        (__attribute__((address_space(3))) unsigned int*)(vbuf[buf] + l0*16),
        16, 0, 0);
    }
  };

  f32x16 o0 = (f32x16)0.f, o1 = (f32x16)0.f;
  float psum0 = 0.f, psum1 = 0.f;
  // exp(s*scale - 8) == exp2(s*c1 - c2): one v_fma + one native v_exp_f32
  const float c1 = 0.125f * 1.44269504f;
  const float c2 = 8.f * 1.44269504f;
  const int rx = q5 & 7;        // row-XOR class for this lane's fragment rows

  stage(0, 0);
  asm volatile("s_waitcnt vmcnt(0)");
  __syncthreads();

  const int NT = TSEQ/KSPLIT/KVBLK;   // 8
  for (int kt = 0; kt < NT; kt++) {
    int cur = kt & 1;
    if (kt + 1 < NT) stage(cur ^ 1, kt + 1);

    #pragma unroll
    for (int t=0;t<2;t++) {
      // K fragments from swizzled LDS: row = t*32+q5, d-chunk = c*2+hi
      bf16x8 kf[4];
      #pragma unroll
      for (int c=0;c<4;c++)
        kf[c] = *(const bf16x8*)(kbuf[cur] + (t*32+q5)*128 + (((c*2+hi) ^ rx)*16));

      f32x16 st = (f32x16)0.f;
      __builtin_amdgcn_s_setprio(1);
      #pragma unroll
      for (int c=0;c<4;c++)
        st = __builtin_amdgcn_mfma_f32_32x32x16_bf16(kf[c], qf[c], st, 0, 0, 0);
      __builtin_amdgcn_s_setprio(0);

      // Vt fragments: rows q5 (o0) and q5+32 (o1), key-chunk = t*4+ks2*2+hi
      bf16x8 vf0[2], vf1[2];
      #pragma unroll
      for (int ks2=0;ks2<2;ks2++) {
        int kc = ((t*4 + ks2*2 + hi) ^ rx)*16;
        vf0[ks2] = *(const bf16x8*)(vbuf[cur] + q5*128 + kc);
        vf1[ks2] = *(const bf16x8*)(vbuf[cur] + (q5+32)*128 + kc);
      }

      #pragma unroll
      for (int i=0;i<16;i+=2) {
        st[i]   = __builtin_amdgcn_exp2f(st[i]*c1   - c2);
        st[i+1] = __builtin_amdgcn_exp2f(st[i+1]*c1 - c2);
        psum0 += st[i];
        psum1 += st[i+1];
      }
      unsigned pw[4][2];
      #pragma unroll
      for (int a=0;a<4;a++)
        #pragma unroll
        for (int p=0;p<2;p++) {
          union { __hip_bfloat162 h; unsigned u; } cvp;
          cvp.h = __float22bfloat162_rn(float2{st[a*4+2*p], st[a*4+2*p+1]});
          pw[a][p] = cvp.u;
        }
      // B-frag build via permlane32_swap self-swaps (T12):
      //   u[0] = pw[2k][0][lane&31]        = swap(pw).x
      //   u[2] = pw[2k+1][0][(lane&31)|32] = swap(pw).y
      #pragma unroll
      for (int ks2=0;ks2<2;ks2++) {
        uint32x2 s0 = __builtin_amdgcn_permlane32_swap(pw[2*ks2][0],   pw[2*ks2][0],   false, false);
        uint32x2 s1 = __builtin_amdgcn_permlane32_swap(pw[2*ks2][1],   pw[2*ks2][1],   false, false);
        uint32x2 s2 = __builtin_amdgcn_permlane32_swap(pw[2*ks2+1][0], pw[2*ks2+1][0], false, false);
        uint32x2 s3 = __builtin_amdgcn_permlane32_swap(pw[2*ks2+1][1], pw[2*ks2+1][1], false, false);
        union { unsigned u[4]; bf16x8 v; } bw;
        bw.u[0] = s0[0];
        bw.u[1] = s1[0];
        bw.u[2] = s2[1];
        bw.u[3] = s3[1];
        __builtin_amdgcn_s_setprio(1);
        o0 = __builtin_amdgcn_mfma_f32_32x32x16_bf16(vf0[ks2], bw.v, o0, 0, 0, 0);
        o1 = __builtin_amdgcn_mfma_f32_32x32x16_bf16(vf1[ks2], bw.v, o1, 0, 0, 0);
        __builtin_amdgcn_s_setprio(0);
      }
    }

    asm volatile("s_waitcnt vmcnt(0)");
    __syncthreads();
  }

  float psum = psum0 + psum1;
  float ltot = psum + __shfl_xor(psum, 32);
  size_t gq = (size_t)bh*TSEQ + qrow;
  if (!hi) pml[gq*KSPLIT + ks_id] = ltot;

  #pragma unroll
  for (int rg=0; rg<4; rg++) {
    bf16x4 pk0, pk1;
    #pragma unroll
    for (int rj=0;rj<4;rj++) { pk0[rj] = f2bf(o0[rg*4+rj]); pk1[rj] = f2bf(o1[rg*4+rj]); }
    int d0 = rg*8 + hi*4;
    *(bf16x4*)&po[(gq*KSPLIT + ks_id)*HD + d0]      = pk0;
    *(bf16x4*)&po[(gq*KSPLIT + ks_id)*HD + 32 + d0] = pk1;
  }
}

// ---------------- combine split-K partials + shaped epilogue ----------------
__global__ __launch_bounds__(256) void combine_kernel(
    const short* __restrict__ po, const float* __restrict__ pml,
    const short* __restrict__ V, const float* __restrict__ vs,
    const float* __restrict__ alpha, const float* __restrict__ beta,
    const float* __restrict__ gamma, const float* __restrict__ Cc,
    float* __restrict__ out) {
  size_t gq = (size_t)blockIdx.x*4 + (threadIdx.x >> 6);
  int d = threadIdx.x & 63;
  int bh = (int)(gq >> 11), q = (int)(gq & (TSEQ-1));
  int b = bh / HEADS, h = bh % HEADS;

  float L = 0.f, acc = 0.f;
  #pragma unroll
  for (int i=0;i<KSPLIT;i++) {
    L   += pml[gq*KSPLIT + i];
    acc += bf2f(po[(gq*KSPLIT + i)*HD + d]);
  }
  float sv = acc / L;
  float al = alpha[h], be = beta[h], ga = gamma[h], cc = Cc[h];
  float vv = bf2f(V[((size_t)bh*TSEQ + q)*HD + d]);
  out[((size_t)b*TSEQ + q)*DMODEL + h*HD + d] = al*vv + be*sv - ga*cc*vs[bh*HD + d];
}

extern "C" void kernel_launch(void* const* d_in, const int* in_sizes, int n_in,
                              void* d_out, int out_size, void* d_ws, size_t ws_size,
                              hipStream_t stream) {
  const float* x     = (const float*)d_in[0];
  const float* Wq    = (const float*)d_in[1];
  const float* bq    = (const float*)d_in[2];
  const float* Wk    = (const float*)d_in[3];
  const float* bk    = (const float*)d_in[4];
  const float* Wv    = (const float*)d_in[5];
  const float* bv    = (const float*)d_in[6];
  const float* alpha = (const float*)d_in[7];
  const float* beta  = (const float*)d_in[8];
  const float* gamma = (const float*)d_in[9];
  const float* Cc    = (const float*)d_in[10];
  float* out = (float*)d_out;

  char* ws = (char*)d_ws;
  size_t off = 0;
  auto alloc = [&](size_t bytes) -> void* {
    void* p = ws + off; off += (bytes + 255) & ~(size_t)255; return p;
  };
  short* Xb = (short*)alloc((size_t)NTOK*DMODEL*2);
  short* Wc = (short*)alloc((size_t)NQKV*DMODEL*2);
  float* bc = (float*)alloc((size_t)NQKV*4);
  short* Q  = (short*)alloc((size_t)BATCH*HEADS*TSEQ*HD*2);
  short* K  = (short*)alloc((size_t)BATCH*HEADS*TSEQ*HD*2);
  short* V  = (short*)alloc((size_t)BATCH*HEADS*TSEQ*HD*2);
  short* Vt = (short*)alloc((size_t)BATCH*HEADS*TSEQ*HD*2);
  float* vs = (float*)alloc((size_t)BATCH*HEADS*HD*4);
  float* part = (float*)alloc((size_t)BATCH*HEADS*8*HD*4);
  short* po  = (short*)alloc((size_t)BATCH*HEADS*TSEQ*KSPLIT*HD*2);   // 25.2 MB
  float* pml = (float*)alloc((size_t)BATCH*HEADS*TSEQ*KSPLIT*4);      // 0.8 MB

  cvt_kernel<<<1024, 256, 0, stream>>>(x, Wq, Wk, Wv, bq, bk, bv, Xb, Wc, bc);
  qkv_gemm<<<(NTOK/128)*(NQKV/128), 256, 0, stream>>>(Xb, Wc, bc, Q, K, V, Vt);
  vsum1<<<BATCH*HEADS*8, 256, 0, stream>>>(V, part);
  vsum2<<<BATCH*HEADS, 64, 0, stream>>>(part, vs);
  attn_kernel<<<BATCH*HEADS*(TSEQ/128)*KSPLIT, 256, 0, stream>>>(Q, K, Vt, po, pml);
  combine_kernel<<<BATCH*HEADS*TSEQ/4, 256, 0, stream>>>(po, pml, V, vs, alpha, beta, gamma, Cc, out);
}

// Round 13
// 94.090 us; speedup vs baseline: 1.1517x; 1.0213x over previous
//
#include <hip/hip_runtime.h>
#include <hip/hip_bf16.h>

#define HEADS 12
#define HD 64
#define DMODEL 768
#define TSEQ 2048
#define BATCH 2
#define NTOK (BATCH*TSEQ)   // 4096
#define NQKV (3*DMODEL)     // 2304
#define KSPLIT 4
#define BK 64
#define KVBLK 64

typedef __attribute__((ext_vector_type(8))) short bf16x8;
typedef __attribute__((ext_vector_type(4))) short bf16x4;
typedef __attribute__((ext_vector_type(4))) float f32x4;
typedef __attribute__((ext_vector_type(16))) float f32x16;
typedef __attribute__((ext_vector_type(2))) unsigned uint32x2;

static __device__ inline float bf2f(short s) {
  union { float f; unsigned u; } cv; cv.u = ((unsigned)(unsigned short)s) << 16; return cv.f;
}
static __device__ inline short f2bf(float f) {
  union { float f; unsigned u; } cv; cv.f = f;
  unsigned u = cv.u;
  unsigned r = u + 0x7FFF + ((u >> 16) & 1);   // RNE
  return (short)(r >> 16);
}

// ---------------- conversion / packing (vectorized) ----------------
__global__ void cvt_kernel(const float* __restrict__ x,
                           const float* __restrict__ Wq, const float* __restrict__ Wk,
                           const float* __restrict__ Wv,
                           const float* __restrict__ bq, const float* __restrict__ bk,
                           const float* __restrict__ bv,
                           short* __restrict__ Xb, short* __restrict__ Wc,
                           float* __restrict__ bc) {
  const int NX4 = NTOK*DMODEL/4;          // 786432
  const int WSZ = DMODEL*DMODEL;          // 589824
  const int NW4 = 3*WSZ/4;                // 442368
  const int total = NX4 + NW4 + NQKV;
  for (int i = blockIdx.x*blockDim.x + threadIdx.x; i < total; i += gridDim.x*blockDim.x) {
    if (i < NX4) {
      f32x4 v = *(const f32x4*)&x[i*4];
      bf16x4 o;
      #pragma unroll
      for (int j=0;j<4;j++) o[j] = f2bf(v[j]);
      *(bf16x4*)&Xb[i*4] = o;
    } else if (i < NX4 + NW4) {
      int j = (i - NX4)*4;
      const float* src = (j < WSZ) ? &Wq[j] : (j < 2*WSZ) ? &Wk[j - WSZ] : &Wv[j - 2*WSZ];
      f32x4 v = *(const f32x4*)src;
      bf16x4 o;
      #pragma unroll
      for (int jj=0;jj<4;jj++) o[jj] = f2bf(v[jj]);
      *(bf16x4*)&Wc[j] = o;
    } else {
      int o = i - NX4 - NW4;
      bc[o] = (o < DMODEL) ? bq[o] : (o < 2*DMODEL) ? bk[o - DMODEL] : bv[o - 2*DMODEL];
    }
  }
}

// ---------------- fused QKV GEMM + V column-sum epilogue ----------------
__global__ __launch_bounds__(256,2) void qkv_gemm(const short* __restrict__ Xb,
                                                  const short* __restrict__ Wc,
                                                  const float* __restrict__ bc,
                                                  short* __restrict__ Q, short* __restrict__ K,
                                                  short* __restrict__ V, short* __restrict__ Vt,
                                                  float* __restrict__ vs) {
  __shared__ __align__(16) char lds[65536];   // A0|B0|A1|B1 = 4 x 16KB
  const int nbn = NQKV/128;           // 18
  int swzb = ((blockIdx.x & 7) * 72) + (blockIdx.x >> 3);
  int bm = swzb / nbn, bn = swzb % nbn;
  int trow = bm*128, tcol = bn*128;
  int tid = threadIdx.x;
  int w = tid >> 6, l = tid & 63;
  int wr = w >> 1, wc = w & 1;
  int lr = l & 15, lg = l >> 4;

  int rbase = tid >> 3;
  int csw   = (tid & 7) ^ (rbase & 7);
  const short* pA = Xb + (size_t)(trow + rbase)*DMODEL + csw*8;
  const short* pB = Wc + (size_t)(tcol + rbase)*DMODEL + csw*8;

  unsigned aoff[4][2], boff[4][2];
  #pragma unroll
  for (int m=0;m<4;m++)
    #pragma unroll
    for (int kc2=0;kc2<2;kc2++) {
      int rowa = wr*64 + m*16 + lr;
      aoff[m][kc2] = rowa*128 + (((kc2*4+lg) ^ (rowa&7))*16);
      int rowb = wc*64 + m*16 + lr;
      boff[m][kc2] = rowb*128 + (((kc2*4+lg) ^ (rowb&7))*16);
    }

  f32x4 acc[4][4];
  #pragma unroll
  for (int m=0;m<4;m++)
    #pragma unroll
    for (int n=0;n<4;n++) acc[m][n] = (f32x4)0.f;

  auto stage = [&](int buf, int ks) {
    int k0 = ks*BK;
    unsigned base = (unsigned)buf*32768u;
    #pragma unroll
    for (int i=0;i<4;i++) {
      __builtin_amdgcn_global_load_lds(
        (const __attribute__((address_space(1))) unsigned int*)(pA + k0 + i*(32*DMODEL)),
        (__attribute__((address_space(3))) unsigned int*)(lds + base + (i*256 + w*64)*16),
        16, 0, 0);
      __builtin_amdgcn_global_load_lds(
        (const __attribute__((address_space(1))) unsigned int*)(pB + k0 + i*(32*DMODEL)),
        (__attribute__((address_space(3))) unsigned int*)(lds + base + 16384 + (i*256 + w*64)*16),
        16, 0, 0);
    }
  };

  stage(0, 0);
  asm volatile("s_waitcnt vmcnt(0)");
  __syncthreads();

  const int NKS = DMODEL/BK;   // 12
  for (int ks = 0; ks < NKS; ks++) {
    int cur = ks & 1;
    if (ks + 1 < NKS) stage(cur ^ 1, ks + 1);
    unsigned abase = (unsigned)cur*32768u, bbase = abase + 16384u;
    bf16x8 af[4][2], bfr[4][2];
    #pragma unroll
    for (int m=0;m<4;m++)
      #pragma unroll
      for (int kc2=0;kc2<2;kc2++) {
        af[m][kc2]  = *(const bf16x8*)(lds + abase + aoff[m][kc2]);
        bfr[m][kc2] = *(const bf16x8*)(lds + bbase + boff[m][kc2]);
      }
    __builtin_amdgcn_s_setprio(1);
    #pragma unroll
    for (int m=0;m<4;m++)
      #pragma unroll
      for (int n=0;n<4;n++)
        #pragma unroll
        for (int kc2=0;kc2<2;kc2++)
          acc[m][n] = __builtin_amdgcn_mfma_f32_16x16x32_bf16(af[m][kc2], bfr[n][kc2], acc[m][n], 0, 0, 0);
    __builtin_amdgcn_s_setprio(0);
    __syncthreads();
  }

  // ---- epilogue: stage 128x128 bf16 tile in LDS, coalesced stores ----
  short* ltile = (short*)lds;
  float bcv[4];
  #pragma unroll
  for (int n=0;n<4;n++) bcv[n] = bc[tcol + wc*64 + n*16 + lr];
  #pragma unroll
  for (int m=0;m<4;m++)
    #pragma unroll
    for (int n=0;n<4;n++)
      #pragma unroll
      for (int j=0;j<4;j++)
        ltile[(wr*64 + m*16 + lg*4 + j)*128 + wc*64 + n*16 + lr] = f2bf(acc[m][n][j] + bcv[n]);
  __syncthreads();

  int sel = tcol / DMODEL;            // 0=Q 1=K 2=V
  int h0  = (tcol % DMODEL) >> 6;
  short* dstQKV = (sel == 0) ? Q : (sel == 1) ? K : V;
  #pragma unroll
  for (int rr=0; rr<8; rr++) {
    int idx = rr*256 + tid;
    int r2 = idx >> 4, c2 = idx & 15;
    int t = trow + r2;
    int b = t >> 11, tt = t & (TSEQ-1);
    int hh = h0 + (c2 >> 3), d0 = (c2 & 7)*8;
    bf16x8 val = *(const bf16x8*)&ltile[r2*128 + c2*8];
    *(bf16x8*)&dstQKV[((size_t)(b*HEADS + hh)*TSEQ + tt)*HD + d0] = val;
  }
  if (sel == 2) {
    #pragma unroll
    for (int rr=0; rr<8; rr++) {
      int idx = rr*256 + tid;
      int col = idx >> 4, tc8 = idx & 15;
      int hh = h0 + (col >> 6), d = col & 63;
      int t0 = trow + tc8*8;
      int b = t0 >> 11, tt0 = t0 & (TSEQ-1);
      bf16x8 v;
      #pragma unroll
      for (int j=0;j<8;j++) v[j] = ltile[(tc8*8 + j)*128 + col];
      *(bf16x8*)&Vt[((size_t)(b*HEADS + hh)*HD + d)*TSEQ + tt0] = v;
    }
    // fused V column-sum: each thread sums a half-column of the tile, atomic into vs
    int col = tid & 127;
    int rh  = tid >> 7;          // 0..1
    float s = 0.f;
    #pragma unroll
    for (int i=0;i<64;i++) s += bf2f(ltile[(rh*64 + i)*128 + col]);
    int hh = h0 + (col >> 6), d = col & 63;
    int b = trow >> 11;
    atomicAdd(&vs[(b*HEADS + hh)*HD + d], s);
  }
}

// ---------------- flash attention: 32x32 MFMA, LDS-staged K/Vt (swizzled), static max ----------------
__global__ __launch_bounds__(256,3) void attn_kernel(
    const short* __restrict__ Q, const short* __restrict__ K,
    const short* __restrict__ Vt,
    short* __restrict__ po, float* __restrict__ pml) {
  const int nqt = TSEQ/128;            // 16
  int bid = blockIdx.x;
  int ks_id = bid % KSPLIT;
  int r = bid / KSPLIT;
  int qt = r % nqt;
  int bh = r / nqt;

  int tid = threadIdx.x;
  int w = tid >> 6, lane = tid & 63;
  int q5 = lane & 31, hi = lane >> 5;
  int qrow = qt*128 + w*32 + q5;

  __shared__ __align__(16) char kbuf[2][8192];
  __shared__ __align__(16) char vbuf[2][8192];

  const short* Qp  = Q  + (size_t)bh*TSEQ*HD;
  const short* Kp  = K  + (size_t)bh*TSEQ*HD;
  const short* Vtp = Vt + (size_t)bh*HD*TSEQ;

  bf16x8 qf[4];
  #pragma unroll
  for (int c=0;c<4;c++)
    qf[c] = *(const bf16x8*)&Qp[(size_t)qrow*HD + c*16 + hi*8];

  const int ksoff = ks_id*(TSEQ/KSPLIT);   // 512-key slice

  auto stage = [&](int buf, int kt) {
    int kb = ksoff + kt*KVBLK;
    #pragma unroll
    for (int i=0;i<2;i++) {
      int l0 = i*256 + w*64;
      int l  = l0 + lane;
      int rr = l >> 3, cc = l & 7;
      int sk = cc ^ (rr & 7);
      __builtin_amdgcn_global_load_lds(
        (const __attribute__((address_space(1))) unsigned int*)(Kp + (size_t)(kb + rr)*HD + sk*8),
        (__attribute__((address_space(3))) unsigned int*)(kbuf[buf] + l0*16),
        16, 0, 0);
      __builtin_amdgcn_global_load_lds(
        (const __attribute__((address_space(1))) unsigned int*)(Vtp + (size_t)rr*TSEQ + kb + sk*8),
        (__attribute__((address_space(3))) unsigned int*)(vbuf[buf] + l0*16),
        16, 0, 0);
    }
  };

  f32x16 o0 = (f32x16)0.f, o1 = (f32x16)0.f;
  float psum0 = 0.f, psum1 = 0.f;
  const float c1 = 0.125f * 1.44269504f;
  const float c2 = 8.f * 1.44269504f;
  const int rx = q5 & 7;

  stage(0, 0);
  asm volatile("s_waitcnt vmcnt(0)");
  __syncthreads();

  const int NT = TSEQ/KSPLIT/KVBLK;   // 8
  for (int kt = 0; kt < NT; kt++) {
    int cur = kt & 1;
    if (kt + 1 < NT) stage(cur ^ 1, kt + 1);

    #pragma unroll
    for (int t=0;t<2;t++) {
      bf16x8 kf[4];
      #pragma unroll
      for (int c=0;c<4;c++)
        kf[c] = *(const bf16x8*)(kbuf[cur] + (t*32+q5)*128 + (((c*2+hi) ^ rx)*16));

      f32x16 st = (f32x16)0.f;
      __builtin_amdgcn_s_setprio(1);
      #pragma unroll
      for (int c=0;c<4;c++)
        st = __builtin_amdgcn_mfma_f32_32x32x16_bf16(kf[c], qf[c], st, 0, 0, 0);
      __builtin_amdgcn_s_setprio(0);

      bf16x8 vf0[2], vf1[2];
      #pragma unroll
      for (int ks2=0;ks2<2;ks2++) {
        int kc = ((t*4 + ks2*2 + hi) ^ rx)*16;
        vf0[ks2] = *(const bf16x8*)(vbuf[cur] + q5*128 + kc);
        vf1[ks2] = *(const bf16x8*)(vbuf[cur] + (q5+32)*128 + kc);
      }

      #pragma unroll
      for (int i=0;i<16;i+=2) {
        st[i]   = __builtin_amdgcn_exp2f(st[i]*c1   - c2);
        st[i+1] = __builtin_amdgcn_exp2f(st[i+1]*c1 - c2);
        psum0 += st[i];
        psum1 += st[i+1];
      }
      unsigned pw[4][2];
      #pragma unroll
      for (int a=0;a<4;a++)
        #pragma unroll
        for (int p=0;p<2;p++) {
          union { __hip_bfloat162 h; unsigned u; } cvp;
          cvp.h = __float22bfloat162_rn(float2{st[a*4+2*p], st[a*4+2*p+1]});
          pw[a][p] = cvp.u;
        }
      #pragma unroll
      for (int ks2=0;ks2<2;ks2++) {
        uint32x2 s0 = __builtin_amdgcn_permlane32_swap(pw[2*ks2][0],   pw[2*ks2][0],   false, false);
        uint32x2 s1 = __builtin_amdgcn_permlane32_swap(pw[2*ks2][1],   pw[2*ks2][1],   false, false);
        uint32x2 s2 = __builtin_amdgcn_permlane32_swap(pw[2*ks2+1][0], pw[2*ks2+1][0], false, false);
        uint32x2 s3 = __builtin_amdgcn_permlane32_swap(pw[2*ks2+1][1], pw[2*ks2+1][1], false, false);
        union { unsigned u[4]; bf16x8 v; } bw;
        bw.u[0] = s0[0];
        bw.u[1] = s1[0];
        bw.u[2] = s2[1];
        bw.u[3] = s3[1];
        __builtin_amdgcn_s_setprio(1);
        o0 = __builtin_amdgcn_mfma_f32_32x32x16_bf16(vf0[ks2], bw.v, o0, 0, 0, 0);
        o1 = __builtin_amdgcn_mfma_f32_32x32x16_bf16(vf1[ks2], bw.v, o1, 0, 0, 0);
        __builtin_amdgcn_s_setprio(0);
      }
    }

    asm volatile("s_waitcnt vmcnt(0)");
    __syncthreads();
  }

  float psum = psum0 + psum1;
  float ltot = psum + __shfl_xor(psum, 32);
  size_t gq = (size_t)bh*TSEQ + qrow;
  if (!hi) pml[gq*KSPLIT + ks_id] = ltot;

  #pragma unroll
  for (int rg=0; rg<4; rg++) {
    bf16x4 pk0, pk1;
    #pragma unroll
    for (int rj=0;rj<4;rj++) { pk0[rj] = f2bf(o0[rg*4+rj]); pk1[rj] = f2bf(o1[rg*4+rj]); }
    int d0 = rg*8 + hi*4;
    *(bf16x4*)&po[(gq*KSPLIT + ks_id)*HD + d0]      = pk0;
    *(bf16x4*)&po[(gq*KSPLIT + ks_id)*HD + 32 + d0] = pk1;
  }
}

// ---------------- combine split-K partials + shaped epilogue (wide loads) ----------------
__global__ __launch_bounds__(256) void combine_kernel(
    const short* __restrict__ po, const float* __restrict__ pml,
    const short* __restrict__ V, const float* __restrict__ vs,
    const float* __restrict__ alpha, const float* __restrict__ beta,
    const float* __restrict__ gamma, const float* __restrict__ Cc,
    float* __restrict__ out) {
  int t = threadIdx.x;
  size_t gq = (size_t)blockIdx.x*32 + (t >> 3);   // 32 q-rows per block
  int d0 = (t & 7)*8;                              // 8 dims per lane
  int bh = (int)(gq >> 11), q = (int)(gq & (TSEQ-1));
  int b = bh / HEADS, h = bh % HEADS;

  float L = 0.f;
  float acc[8] = {0,0,0,0,0,0,0,0};
  #pragma unroll
  for (int i=0;i<KSPLIT;i++) {
    L += pml[gq*KSPLIT + i];
    bf16x8 p8 = *(const bf16x8*)&po[(gq*KSPLIT + i)*HD + d0];
    #pragma unroll
    for (int j=0;j<8;j++) acc[j] += bf2f(p8[j]);
  }
  float inv = 1.f / L;
  float al = alpha[h], be = beta[h], gc = gamma[h]*Cc[h];
  bf16x8 v8 = *(const bf16x8*)&V[((size_t)bh*TSEQ + q)*HD + d0];
  f32x4 vs0 = *(const f32x4*)&vs[bh*HD + d0];
  f32x4 vs1 = *(const f32x4*)&vs[bh*HD + d0 + 4];
  f32x4 r0, r1;
  #pragma unroll
  for (int j=0;j<4;j++) {
    r0[j] = al*bf2f(v8[j])   + be*acc[j]*inv   - gc*vs0[j];
    r1[j] = al*bf2f(v8[j+4]) + be*acc[j+4]*inv - gc*vs1[j];
  }
  float* op = &out[((size_t)b*TSEQ + q)*DMODEL + h*HD + d0];
  *(f32x4*)op = r0;
  *(f32x4*)(op+4) = r1;
}

extern "C" void kernel_launch(void* const* d_in, const int* in_sizes, int n_in,
                              void* d_out, int out_size, void* d_ws, size_t ws_size,
                              hipStream_t stream) {
  const float* x     = (const float*)d_in[0];
  const float* Wq    = (const float*)d_in[1];
  const float* bq    = (const float*)d_in[2];
  const float* Wk    = (const float*)d_in[3];
  const float* bk    = (const float*)d_in[4];
  const float* Wv    = (const float*)d_in[5];
  const float* bv    = (const float*)d_in[6];
  const float* alpha = (const float*)d_in[7];
  const float* beta  = (const float*)d_in[8];
  const float* gamma = (const float*)d_in[9];
  const float* Cc    = (const float*)d_in[10];
  float* out = (float*)d_out;

  char* ws = (char*)d_ws;
  size_t off = 0;
  auto alloc = [&](size_t bytes) -> void* {
    void* p = ws + off; off += (bytes + 255) & ~(size_t)255; return p;
  };
  short* Xb = (short*)alloc((size_t)NTOK*DMODEL*2);
  short* Wc = (short*)alloc((size_t)NQKV*DMODEL*2);
  float* bc = (float*)alloc((size_t)NQKV*4);
  short* Q  = (short*)alloc((size_t)BATCH*HEADS*TSEQ*HD*2);
  short* K  = (short*)alloc((size_t)BATCH*HEADS*TSEQ*HD*2);
  short* V  = (short*)alloc((size_t)BATCH*HEADS*TSEQ*HD*2);
  short* Vt = (short*)alloc((size_t)BATCH*HEADS*TSEQ*HD*2);
  float* vs = (float*)alloc((size_t)BATCH*HEADS*HD*4);
  short* po  = (short*)alloc((size_t)BATCH*HEADS*TSEQ*KSPLIT*HD*2);   // 25.2 MB
  float* pml = (float*)alloc((size_t)BATCH*HEADS*TSEQ*KSPLIT*4);      // 0.8 MB

  hipMemsetAsync(vs, 0, (size_t)BATCH*HEADS*HD*4, stream);
  cvt_kernel<<<1024, 256, 0, stream>>>(x, Wq, Wk, Wv, bq, bk, bv, Xb, Wc, bc);
  qkv_gemm<<<(NTOK/128)*(NQKV/128), 256, 0, stream>>>(Xb, Wc, bc, Q, K, V, Vt, vs);
  attn_kernel<<<BATCH*HEADS*(TSEQ/128)*KSPLIT, 256, 0, stream>>>(Q, K, Vt, po, pml);
  combine_kernel<<<BATCH*HEADS*TSEQ/32, 256, 0, stream>>>(po, pml, V, vs, alpha, beta, gamma, Cc, out);
}

// Round 14
// 90.595 us; speedup vs baseline: 1.1961x; 1.0386x over previous
//
#include <hip/hip_runtime.h>
#include <hip/hip_bf16.h>

#define HEADS 12
#define HD 64
#define DMODEL 768
#define TSEQ 2048
#define BATCH 2
#define NTOK (BATCH*TSEQ)   // 4096
#define NQKV (3*DMODEL)     // 2304
#define KSPLIT 4
#define BK 64
#define KVBLK 64
#define QSCALE 0.1803368801f   // 0.125 * log2(e); folded into Q so attn exp is bare exp2

typedef __attribute__((ext_vector_type(8))) short bf16x8;
typedef __attribute__((ext_vector_type(4))) short bf16x4;
typedef __attribute__((ext_vector_type(4))) float f32x4;
typedef __attribute__((ext_vector_type(16))) float f32x16;
typedef __attribute__((ext_vector_type(2))) unsigned uint32x2;

static __device__ inline float bf2f(short s) {
  union { float f; unsigned u; } cv; cv.u = ((unsigned)(unsigned short)s) << 16; return cv.f;
}
static __device__ inline short f2bf(float f) {
  union { float f; unsigned u; } cv; cv.f = f;
  unsigned u = cv.u;
  unsigned r = u + 0x7FFF + ((u >> 16) & 1);   // RNE
  return (short)(r >> 16);
}

// ---------------- conversion / packing (vectorized) ----------------
__global__ void cvt_kernel(const float* __restrict__ x,
                           const float* __restrict__ Wq, const float* __restrict__ Wk,
                           const float* __restrict__ Wv,
                           const float* __restrict__ bq, const float* __restrict__ bk,
                           const float* __restrict__ bv,
                           short* __restrict__ Xb, short* __restrict__ Wc,
                           float* __restrict__ bc) {
  const int NX4 = NTOK*DMODEL/4;          // 786432
  const int WSZ = DMODEL*DMODEL;          // 589824
  const int NW4 = 3*WSZ/4;                // 442368
  const int total = NX4 + NW4 + NQKV;
  for (int i = blockIdx.x*blockDim.x + threadIdx.x; i < total; i += gridDim.x*blockDim.x) {
    if (i < NX4) {
      f32x4 v = *(const f32x4*)&x[i*4];
      bf16x4 o;
      #pragma unroll
      for (int j=0;j<4;j++) o[j] = f2bf(v[j]);
      *(bf16x4*)&Xb[i*4] = o;
    } else if (i < NX4 + NW4) {
      int j = (i - NX4)*4;
      const float* src = (j < WSZ) ? &Wq[j] : (j < 2*WSZ) ? &Wk[j - WSZ] : &Wv[j - 2*WSZ];
      f32x4 v = *(const f32x4*)src;
      bf16x4 o;
      #pragma unroll
      for (int jj=0;jj<4;jj++) o[jj] = f2bf(v[jj]);
      *(bf16x4*)&Wc[j] = o;
    } else {
      int o = i - NX4 - NW4;
      bc[o] = (o < DMODEL) ? bq[o] : (o < 2*DMODEL) ? bk[o - DMODEL] : bv[o - 2*DMODEL];
    }
  }
}

// ---------------- fused QKV GEMM, 128x64 tile (1 head/block), LDS dbuf + gload_lds + swizzle ----------------
__global__ __launch_bounds__(256,3) void qkv_gemm(const short* __restrict__ Xb,
                                                  const short* __restrict__ Wc,
                                                  const float* __restrict__ bc,
                                                  short* __restrict__ Q, short* __restrict__ K,
                                                  short* __restrict__ V, short* __restrict__ Vt,
                                                  float* __restrict__ vs) {
  __shared__ __align__(16) char lds[49152];   // A0(16K)|B0(8K)|A1(16K)|B1(8K)
  const int nbn = NQKV/64;            // 36
  // XCD-aware bijective swizzle: 1152 = 8 x 144
  int swzb = ((blockIdx.x & 7) * 144) + (blockIdx.x >> 3);
  int bm = swzb / nbn, bn = swzb % nbn;
  int trow = bm*128, tcol = bn*64;
  int tid = threadIdx.x;
  int w = tid >> 6, l = tid & 63;
  int wr = w >> 1, wc = w & 1;
  int lr = l & 15, lg = l >> 4;

  int rbase = tid >> 3;                 // 0..31
  int csw   = (tid & 7) ^ (rbase & 7);  // inverse-swizzled 16B chunk within row
  const short* pA = Xb + (size_t)(trow + rbase)*DMODEL + csw*8;
  const short* pB = Wc + (size_t)(tcol + rbase)*DMODEL + csw*8;

  unsigned aoff[4][2], boff[2][2];
  #pragma unroll
  for (int m=0;m<4;m++)
    #pragma unroll
    for (int kc2=0;kc2<2;kc2++) {
      int rowa = wr*64 + m*16 + lr;
      aoff[m][kc2] = rowa*128 + (((kc2*4+lg) ^ (rowa&7))*16);
    }
  #pragma unroll
  for (int n=0;n<2;n++)
    #pragma unroll
    for (int kc2=0;kc2<2;kc2++) {
      int rowb = wc*32 + n*16 + lr;
      boff[n][kc2] = rowb*128 + (((kc2*4+lg) ^ (rowb&7))*16);
    }

  f32x4 acc[4][2];
  #pragma unroll
  for (int m=0;m<4;m++)
    #pragma unroll
    for (int n=0;n<2;n++) acc[m][n] = (f32x4)0.f;

  auto stage = [&](int buf, int ks) {
    int k0 = ks*BK;
    unsigned base = (unsigned)buf*24576u;
    #pragma unroll
    for (int i=0;i<4;i++)
      __builtin_amdgcn_global_load_lds(
        (const __attribute__((address_space(1))) unsigned int*)(pA + k0 + i*(32*DMODEL)),
        (__attribute__((address_space(3))) unsigned int*)(lds + base + (i*256 + w*64)*16),
        16, 0, 0);
    #pragma unroll
    for (int i=0;i<2;i++)
      __builtin_amdgcn_global_load_lds(
        (const __attribute__((address_space(1))) unsigned int*)(pB + k0 + i*(32*DMODEL)),
        (__attribute__((address_space(3))) unsigned int*)(lds + base + 16384 + (i*256 + w*64)*16),
        16, 0, 0);
  };

  stage(0, 0);
  asm volatile("s_waitcnt vmcnt(0)");
  __syncthreads();

  const int NKS = DMODEL/BK;   // 12
  for (int ks = 0; ks < NKS; ks++) {
    int cur = ks & 1;
    if (ks + 1 < NKS) stage(cur ^ 1, ks + 1);
    unsigned abase = (unsigned)cur*24576u, bbase = abase + 16384u;
    bf16x8 af[4][2], bfr[2][2];
    #pragma unroll
    for (int m=0;m<4;m++)
      #pragma unroll
      for (int kc2=0;kc2<2;kc2++)
        af[m][kc2] = *(const bf16x8*)(lds + abase + aoff[m][kc2]);
    #pragma unroll
    for (int n=0;n<2;n++)
      #pragma unroll
      for (int kc2=0;kc2<2;kc2++)
        bfr[n][kc2] = *(const bf16x8*)(lds + bbase + boff[n][kc2]);
    __builtin_amdgcn_s_setprio(1);
    #pragma unroll
    for (int m=0;m<4;m++)
      #pragma unroll
      for (int n=0;n<2;n++)
        #pragma unroll
        for (int kc2=0;kc2<2;kc2++)
          acc[m][n] = __builtin_amdgcn_mfma_f32_16x16x32_bf16(af[m][kc2], bfr[n][kc2], acc[m][n], 0, 0, 0);
    __builtin_amdgcn_s_setprio(0);
    __syncthreads();
  }

  // ---- epilogue: stage 128x64 bf16 tile in LDS, coalesced stores ----
  short* ltile = (short*)lds;
  int sel = tcol / DMODEL;            // 0=Q 1=K 2=V
  int hh  = (tcol % DMODEL) >> 6;     // single head
  float qsc = (sel == 0) ? QSCALE : 1.f;
  float bcv[2];
  #pragma unroll
  for (int n=0;n<2;n++) bcv[n] = bc[tcol + wc*32 + n*16 + lr];
  #pragma unroll
  for (int m=0;m<4;m++)
    #pragma unroll
    for (int n=0;n<2;n++)
      #pragma unroll
      for (int j=0;j<4;j++)
        ltile[(wr*64 + m*16 + lg*4 + j)*64 + wc*32 + n*16 + lr] = f2bf((acc[m][n][j] + bcv[n]) * qsc);
  __syncthreads();

  short* dstQKV = (sel == 0) ? Q : (sel == 1) ? K : V;
  int b = trow >> 11;
  #pragma unroll
  for (int rr=0; rr<4; rr++) {
    int idx = rr*256 + tid;           // 1024 chunks of 16B
    int r2 = idx >> 3, c2 = idx & 7;
    int tt = (trow + r2) & (TSEQ-1);
    bf16x8 val = *(const bf16x8*)&ltile[r2*64 + c2*8];
    *(bf16x8*)&dstQKV[((size_t)(b*HEADS + hh)*TSEQ + tt)*HD + c2*8] = val;
  }
  if (sel == 2) {
    #pragma unroll
    for (int rr=0; rr<4; rr++) {
      int idx = rr*256 + tid;         // 64 cols x 16 t-chunks
      int col = idx >> 4, tc8 = idx & 15;
      int tt0 = (trow + tc8*8) & (TSEQ-1);
      bf16x8 v;
      #pragma unroll
      for (int j=0;j<8;j++) v[j] = ltile[(tc8*8 + j)*64 + col];
      *(bf16x8*)&Vt[((size_t)(b*HEADS + hh)*HD + col)*TSEQ + tt0] = v;
    }
    // fused V column-sum: each thread sums a quarter-column, atomic into vs
    int col = tid & 63;
    int rh  = tid >> 6;          // 0..3
    float s = 0.f;
    #pragma unroll
    for (int i=0;i<32;i++) s += bf2f(ltile[(rh*32 + i)*64 + col]);
    atomicAdd(&vs[(b*HEADS + hh)*HD + col], s);
  }
}

// ---------------- flash attention: 32x32 MFMA, LDS-staged K/Vt (swizzled), static max ----------------
__global__ __launch_bounds__(256,3) void attn_kernel(
    const short* __restrict__ Q, const short* __restrict__ K,
    const short* __restrict__ Vt,
    short* __restrict__ po, float* __restrict__ pml) {
  const int nqt = TSEQ/128;            // 16
  int bid = blockIdx.x;
  int ks_id = bid % KSPLIT;
  int r = bid / KSPLIT;
  int qt = r % nqt;
  int bh = r / nqt;

  int tid = threadIdx.x;
  int w = tid >> 6, lane = tid & 63;
  int q5 = lane & 31, hi = lane >> 5;
  int qrow = qt*128 + w*32 + q5;

  __shared__ __align__(16) char kbuf[2][8192];
  __shared__ __align__(16) char vbuf[2][8192];

  const short* Qp  = Q  + (size_t)bh*TSEQ*HD;
  const short* Kp  = K  + (size_t)bh*TSEQ*HD;
  const short* Vtp = Vt + (size_t)bh*HD*TSEQ;

  bf16x8 qf[4];
  #pragma unroll
  for (int c=0;c<4;c++)
    qf[c] = *(const bf16x8*)&Qp[(size_t)qrow*HD + c*16 + hi*8];

  const int ksoff = ks_id*(TSEQ/KSPLIT);   // 512-key slice

  auto stage = [&](int buf, int kt) {
    int kb = ksoff + kt*KVBLK;
    #pragma unroll
    for (int i=0;i<2;i++) {
      int l0 = i*256 + w*64;
      int l  = l0 + lane;
      int rr = l >> 3, cc = l & 7;
      int sk = cc ^ (rr & 7);
      __builtin_amdgcn_global_load_lds(
        (const __attribute__((address_space(1))) unsigned int*)(Kp + (size_t)(kb + rr)*HD + sk*8),
        (__attribute__((address_space(3))) unsigned int*)(kbuf[buf] + l0*16),
        16, 0, 0);
      __builtin_amdgcn_global_load_lds(
        (const __attribute__((address_space(1))) unsigned int*)(Vtp + (size_t)rr*TSEQ + kb + sk*8),
        (__attribute__((address_space(3))) unsigned int*)(vbuf[buf] + l0*16),
        16, 0, 0);
    }
  };

  f32x16 o0 = (f32x16)0.f, o1 = (f32x16)0.f;
  float psum0 = 0.f, psum1 = 0.f;
  const int rx = q5 & 7;

  stage(0, 0);
  asm volatile("s_waitcnt vmcnt(0)");
  __syncthreads();

  const int NT = TSEQ/KSPLIT/KVBLK;   // 8
  for (int kt = 0; kt < NT; kt++) {
    int cur = kt & 1;
    if (kt + 1 < NT) stage(cur ^ 1, kt + 1);

    #pragma unroll
    for (int t=0;t<2;t++) {
      bf16x8 kf[4];
      #pragma unroll
      for (int c=0;c<4;c++)
        kf[c] = *(const bf16x8*)(kbuf[cur] + (t*32+q5)*128 + (((c*2+hi) ^ rx)*16));

      f32x16 st = (f32x16)0.f;
      __builtin_amdgcn_s_setprio(1);
      #pragma unroll
      for (int c=0;c<4;c++)
        st = __builtin_amdgcn_mfma_f32_32x32x16_bf16(kf[c], qf[c], st, 0, 0, 0);
      __builtin_amdgcn_s_setprio(0);

      bf16x8 vf0[2], vf1[2];
      #pragma unroll
      for (int ks2=0;ks2<2;ks2++) {
        int kc = ((t*4 + ks2*2 + hi) ^ rx)*16;
        vf0[ks2] = *(const bf16x8*)(vbuf[cur] + q5*128 + kc);
        vf1[ks2] = *(const bf16x8*)(vbuf[cur] + (q5+32)*128 + kc);
      }

      // Q pre-scaled by 0.125*log2e; the -8 bias cancels in O/L -> bare exp2
      #pragma unroll
      for (int i=0;i<16;i+=2) {
        st[i]   = __builtin_amdgcn_exp2f(st[i]);
        st[i+1] = __builtin_amdgcn_exp2f(st[i+1]);
        psum0 += st[i];
        psum1 += st[i+1];
      }
      unsigned pw[4][2];
      #pragma unroll
      for (int a=0;a<4;a++)
        #pragma unroll
        for (int p=0;p<2;p++) {
          union { __hip_bfloat162 h; unsigned u; } cvp;
          cvp.h = __float22bfloat162_rn(float2{st[a*4+2*p], st[a*4+2*p+1]});
          pw[a][p] = cvp.u;
        }
      #pragma unroll
      for (int ks2=0;ks2<2;ks2++) {
        uint32x2 s0 = __builtin_amdgcn_permlane32_swap(pw[2*ks2][0],   pw[2*ks2][0],   false, false);
        uint32x2 s1 = __builtin_amdgcn_permlane32_swap(pw[2*ks2][1],   pw[2*ks2][1],   false, false);
        uint32x2 s2 = __builtin_amdgcn_permlane32_swap(pw[2*ks2+1][0], pw[2*ks2+1][0], false, false);
        uint32x2 s3 = __builtin_amdgcn_permlane32_swap(pw[2*ks2+1][1], pw[2*ks2+1][1], false, false);
        union { unsigned u[4]; bf16x8 v; } bw;
        bw.u[0] = s0[0];
        bw.u[1] = s1[0];
        bw.u[2] = s2[1];
        bw.u[3] = s3[1];
        __builtin_amdgcn_s_setprio(1);
        o0 = __builtin_amdgcn_mfma_f32_32x32x16_bf16(vf0[ks2], bw.v, o0, 0, 0, 0);
        o1 = __builtin_amdgcn_mfma_f32_32x32x16_bf16(vf1[ks2], bw.v, o1, 0, 0, 0);
        __builtin_amdgcn_s_setprio(0);
      }
    }

    asm volatile("s_waitcnt vmcnt(0)");
    __syncthreads();
  }

  float psum = psum0 + psum1;
  float ltot = psum + __shfl_xor(psum, 32);
  size_t gq = (size_t)bh*TSEQ + qrow;
  if (!hi) pml[gq*KSPLIT + ks_id] = ltot;

  #pragma unroll
  for (int rg=0; rg<4; rg++) {
    bf16x4 pk0, pk1;
    #pragma unroll
    for (int rj=0;rj<4;rj++) { pk0[rj] = f2bf(o0[rg*4+rj]); pk1[rj] = f2bf(o1[rg*4+rj]); }
    int d0 = rg*8 + hi*4;
    *(bf16x4*)&po[(gq*KSPLIT + ks_id)*HD + d0]      = pk0;
    *(bf16x4*)&po[(gq*KSPLIT + ks_id)*HD + 32 + d0] = pk1;
  }
}

// ---------------- combine split-K partials + shaped epilogue (wide loads) ----------------
__global__ __launch_bounds__(256) void combine_kernel(
    const short* __restrict__ po, const float* __restrict__ pml,
    const short* __restrict__ V, const float* __restrict__ vs,
    const float* __restrict__ alpha, const float* __restrict__ beta,
    const float* __restrict__ gamma, const float* __restrict__ Cc,
    float* __restrict__ out) {
  int t = threadIdx.x;
  size_t gq = (size_t)blockIdx.x*32 + (t >> 3);   // 32 q-rows per block
  int d0 = (t & 7)*8;                              // 8 dims per lane
  int bh = (int)(gq >> 11), q = (int)(gq & (TSEQ-1));
  int b = bh / HEADS, h = bh % HEADS;

  float L = 0.f;
  float acc[8] = {0,0,0,0,0,0,0,0};
  #pragma unroll
  for (int i=0;i<KSPLIT;i++) {
    L += pml[gq*KSPLIT + i];
    bf16x8 p8 = *(const bf16x8*)&po[(gq*KSPLIT + i)*HD + d0];
    #pragma unroll
    for (int j=0;j<8;j++) acc[j] += bf2f(p8[j]);
  }
  float inv = 1.f / L;
  float al = alpha[h], be = beta[h], gc = gamma[h]*Cc[h];
  bf16x8 v8 = *(const bf16x8*)&V[((size_t)bh*TSEQ + q)*HD + d0];
  f32x4 vs0 = *(const f32x4*)&vs[bh*HD + d0];
  f32x4 vs1 = *(const f32x4*)&vs[bh*HD + d0 + 4];
  f32x4 r0, r1;
  #pragma unroll
  for (int j=0;j<4;j++) {
    r0[j] = al*bf2f(v8[j])   + be*acc[j]*inv   - gc*vs0[j];
    r1[j] = al*bf2f(v8[j+4]) + be*acc[j+4]*inv - gc*vs1[j];
  }
  float* op = &out[((size_t)b*TSEQ + q)*DMODEL + h*HD + d0];
  *(f32x4*)op = r0;
  *(f32x4*)(op+4) = r1;
}

extern "C" void kernel_launch(void* const* d_in, const int* in_sizes, int n_in,
                              void* d_out, int out_size, void* d_ws, size_t ws_size,
                              hipStream_t stream) {
  const float* x     = (const float*)d_in[0];
  const float* Wq    = (const float*)d_in[1];
  const float* bq    = (const float*)d_in[2];
  const float* Wk    = (const float*)d_in[3];
  const float* bk    = (const float*)d_in[4];
  const float* Wv    = (const float*)d_in[5];
  const float* bv    = (const float*)d_in[6];
  const float* alpha = (const float*)d_in[7];
  const float* beta  = (const float*)d_in[8];
  const float* gamma = (const float*)d_in[9];
  const float* Cc    = (const float*)d_in[10];
  float* out = (float*)d_out;

  char* ws = (char*)d_ws;
  size_t off = 0;
  auto alloc = [&](size_t bytes) -> void* {
    void* p = ws + off; off += (bytes + 255) & ~(size_t)255; return p;
  };
  short* Xb = (short*)alloc((size_t)NTOK*DMODEL*2);
  short* Wc = (short*)alloc((size_t)NQKV*DMODEL*2);
  float* bc = (float*)alloc((size_t)NQKV*4);
  short* Q  = (short*)alloc((size_t)BATCH*HEADS*TSEQ*HD*2);
  short* K  = (short*)alloc((size_t)BATCH*HEADS*TSEQ*HD*2);
  short* V  = (short*)alloc((size_t)BATCH*HEADS*TSEQ*HD*2);
  short* Vt = (short*)alloc((size_t)BATCH*HEADS*TSEQ*HD*2);
  float* vs = (float*)alloc((size_t)BATCH*HEADS*HD*4);
  short* po  = (short*)alloc((size_t)BATCH*HEADS*TSEQ*KSPLIT*HD*2);   // 25.2 MB
  float* pml = (float*)alloc((size_t)BATCH*HEADS*TSEQ*KSPLIT*4);      // 0.8 MB

  hipMemsetAsync(vs, 0, (size_t)BATCH*HEADS*HD*4, stream);
  cvt_kernel<<<1024, 256, 0, stream>>>(x, Wq, Wk, Wv, bq, bk, bv, Xb, Wc, bc);
  qkv_gemm<<<(NTOK/128)*(NQKV/64), 256, 0, stream>>>(Xb, Wc, bc, Q, K, V, Vt, vs);
  attn_kernel<<<BATCH*HEADS*(TSEQ/128)*KSPLIT, 256, 0, stream>>>(Q, K, Vt, po, pml);
  combine_kernel<<<BATCH*HEADS*TSEQ/32, 256, 0, stream>>>(po, pml, V, vs, alpha, beta, gamma, Cc, out);
}

// Round 15
// 87.392 us; speedup vs baseline: 1.2399x; 1.0367x over previous
//
#include <hip/hip_runtime.h>
#include <hip/hip_bf16.h>

#define HEADS 12
#define HD 64
#define DMODEL 768
#define TSEQ 2048
#define BATCH 2
#define NTOK (BATCH*TSEQ)   // 4096
#define NQKV (3*DMODEL)     // 2304
#define KSPLIT 2
#define BK 64
#define KVBLK 64
#define QSCALE 0.1803368801f   // 0.125 * log2(e); folded into Q so attn exp is bare exp2

typedef __attribute__((ext_vector_type(8))) short bf16x8;
typedef __attribute__((ext_vector_type(4))) short bf16x4;
typedef __attribute__((ext_vector_type(4))) float f32x4;
typedef __attribute__((ext_vector_type(16))) float f32x16;
typedef __attribute__((ext_vector_type(2))) unsigned uint32x2;

static __device__ inline float bf2f(short s) {
  union { float f; unsigned u; } cv; cv.u = ((unsigned)(unsigned short)s) << 16; return cv.f;
}
static __device__ inline short f2bf(float f) {
  union { float f; unsigned u; } cv; cv.f = f;
  unsigned u = cv.u;
  unsigned r = u + 0x7FFF + ((u >> 16) & 1);   // RNE
  return (short)(r >> 16);
}

// ---------------- conversion / packing (vectorized) ----------------
__global__ void cvt_kernel(const float* __restrict__ x,
                           const float* __restrict__ Wq, const float* __restrict__ Wk,
                           const float* __restrict__ Wv,
                           const float* __restrict__ bq, const float* __restrict__ bk,
                           const float* __restrict__ bv,
                           short* __restrict__ Xb, short* __restrict__ Wc,
                           float* __restrict__ bc) {
  const int NX4 = NTOK*DMODEL/4;          // 786432
  const int WSZ = DMODEL*DMODEL;          // 589824
  const int NW4 = 3*WSZ/4;                // 442368
  const int total = NX4 + NW4 + NQKV;
  for (int i = blockIdx.x*blockDim.x + threadIdx.x; i < total; i += gridDim.x*blockDim.x) {
    if (i < NX4) {
      f32x4 v = *(const f32x4*)&x[i*4];
      bf16x4 o;
      #pragma unroll
      for (int j=0;j<4;j++) o[j] = f2bf(v[j]);
      *(bf16x4*)&Xb[i*4] = o;
    } else if (i < NX4 + NW4) {
      int j = (i - NX4)*4;
      const float* src = (j < WSZ) ? &Wq[j] : (j < 2*WSZ) ? &Wk[j - WSZ] : &Wv[j - 2*WSZ];
      f32x4 v = *(const f32x4*)src;
      bf16x4 o;
      #pragma unroll
      for (int jj=0;jj<4;jj++) o[jj] = f2bf(v[jj]);
      *(bf16x4*)&Wc[j] = o;
    } else {
      int o = i - NX4 - NW4;
      bc[o] = (o < DMODEL) ? bq[o] : (o < 2*DMODEL) ? bk[o - DMODEL] : bv[o - 2*DMODEL];
    }
  }
}

// ---------------- fused QKV GEMM, 128x64 tile (1 head/block), LDS dbuf + gload_lds + swizzle ----------------
__global__ __launch_bounds__(256,3) void qkv_gemm(const short* __restrict__ Xb,
                                                  const short* __restrict__ Wc,
                                                  const float* __restrict__ bc,
                                                  short* __restrict__ Q, short* __restrict__ K,
                                                  short* __restrict__ V, short* __restrict__ Vt,
                                                  float* __restrict__ vs) {
  __shared__ __align__(16) char lds[49152];   // A0(16K)|B0(8K)|A1(16K)|B1(8K)
  const int nbn = NQKV/64;            // 36
  // XCD-aware bijective swizzle: 1152 = 8 x 144
  int swzb = ((blockIdx.x & 7) * 144) + (blockIdx.x >> 3);
  int bm = swzb / nbn, bn = swzb % nbn;
  int trow = bm*128, tcol = bn*64;
  int tid = threadIdx.x;
  int w = tid >> 6, l = tid & 63;
  int wr = w >> 1, wc = w & 1;
  int lr = l & 15, lg = l >> 4;

  int rbase = tid >> 3;                 // 0..31
  int csw   = (tid & 7) ^ (rbase & 7);  // inverse-swizzled 16B chunk within row
  const short* pA = Xb + (size_t)(trow + rbase)*DMODEL + csw*8;
  const short* pB = Wc + (size_t)(tcol + rbase)*DMODEL + csw*8;

  unsigned aoff[4][2], boff[2][2];
  #pragma unroll
  for (int m=0;m<4;m++)
    #pragma unroll
    for (int kc2=0;kc2<2;kc2++) {
      int rowa = wr*64 + m*16 + lr;
      aoff[m][kc2] = rowa*128 + (((kc2*4+lg) ^ (rowa&7))*16);
    }
  #pragma unroll
  for (int n=0;n<2;n++)
    #pragma unroll
    for (int kc2=0;kc2<2;kc2++) {
      int rowb = wc*32 + n*16 + lr;
      boff[n][kc2] = rowb*128 + (((kc2*4+lg) ^ (rowb&7))*16);
    }

  f32x4 acc[4][2];
  #pragma unroll
  for (int m=0;m<4;m++)
    #pragma unroll
    for (int n=0;n<2;n++) acc[m][n] = (f32x4)0.f;

  auto stage = [&](int buf, int ks) {
    int k0 = ks*BK;
    unsigned base = (unsigned)buf*24576u;
    #pragma unroll
    for (int i=0;i<4;i++)
      __builtin_amdgcn_global_load_lds(
        (const __attribute__((address_space(1))) unsigned int*)(pA + k0 + i*(32*DMODEL)),
        (__attribute__((address_space(3))) unsigned int*)(lds + base + (i*256 + w*64)*16),
        16, 0, 0);
    #pragma unroll
    for (int i=0;i<2;i++)
      __builtin_amdgcn_global_load_lds(
        (const __attribute__((address_space(1))) unsigned int*)(pB + k0 + i*(32*DMODEL)),
        (__attribute__((address_space(3))) unsigned int*)(lds + base + 16384 + (i*256 + w*64)*16),
        16, 0, 0);
  };

  stage(0, 0);
  asm volatile("s_waitcnt vmcnt(0)" ::: "memory");
  __syncthreads();

  const int NKS = DMODEL/BK;   // 12
  for (int ks = 0; ks < NKS; ks++) {
    int cur = ks & 1;
    if (ks + 1 < NKS) stage(cur ^ 1, ks + 1);
    unsigned abase = (unsigned)cur*24576u, bbase = abase + 16384u;
    bf16x8 af[4][2], bfr[2][2];
    #pragma unroll
    for (int m=0;m<4;m++)
      #pragma unroll
      for (int kc2=0;kc2<2;kc2++)
        af[m][kc2] = *(const bf16x8*)(lds + abase + aoff[m][kc2]);
    #pragma unroll
    for (int n=0;n<2;n++)
      #pragma unroll
      for (int kc2=0;kc2<2;kc2++)
        bfr[n][kc2] = *(const bf16x8*)(lds + bbase + boff[n][kc2]);
    __builtin_amdgcn_s_setprio(1);
    #pragma unroll
    for (int m=0;m<4;m++)
      #pragma unroll
      for (int n=0;n<2;n++)
        #pragma unroll
        for (int kc2=0;kc2<2;kc2++)
          acc[m][n] = __builtin_amdgcn_mfma_f32_16x16x32_bf16(af[m][kc2], bfr[n][kc2], acc[m][n], 0, 0, 0);
    __builtin_amdgcn_s_setprio(0);
    __syncthreads();
  }

  // ---- epilogue: stage 128x64 bf16 tile in LDS, coalesced stores ----
  short* ltile = (short*)lds;
  int sel = tcol / DMODEL;            // 0=Q 1=K 2=V
  int hh  = (tcol % DMODEL) >> 6;     // single head
  float qsc = (sel == 0) ? QSCALE : 1.f;
  float bcv[2];
  #pragma unroll
  for (int n=0;n<2;n++) bcv[n] = bc[tcol + wc*32 + n*16 + lr];
  #pragma unroll
  for (int m=0;m<4;m++)
    #pragma unroll
    for (int n=0;n<2;n++)
      #pragma unroll
      for (int j=0;j<4;j++)
        ltile[(wr*64 + m*16 + lg*4 + j)*64 + wc*32 + n*16 + lr] = f2bf((acc[m][n][j] + bcv[n]) * qsc);
  __syncthreads();

  short* dstQKV = (sel == 0) ? Q : (sel == 1) ? K : V;
  int b = trow >> 11;
  #pragma unroll
  for (int rr=0; rr<4; rr++) {
    int idx = rr*256 + tid;           // 1024 chunks of 16B
    int r2 = idx >> 3, c2 = idx & 7;
    int tt = (trow + r2) & (TSEQ-1);
    bf16x8 val = *(const bf16x8*)&ltile[r2*64 + c2*8];
    *(bf16x8*)&dstQKV[((size_t)(b*HEADS + hh)*TSEQ + tt)*HD + c2*8] = val;
  }
  if (sel == 2) {
    #pragma unroll
    for (int rr=0; rr<4; rr++) {
      int idx = rr*256 + tid;         // 64 cols x 16 t-chunks
      int col = idx >> 4, tc8 = idx & 15;
      int tt0 = (trow + tc8*8) & (TSEQ-1);
      bf16x8 v;
      #pragma unroll
      for (int j=0;j<8;j++) v[j] = ltile[(tc8*8 + j)*64 + col];
      *(bf16x8*)&Vt[((size_t)(b*HEADS + hh)*HD + col)*TSEQ + tt0] = v;
    }
    // fused V column-sum: each thread sums a quarter-column, atomic into vs
    int col = tid & 63;
    int rh  = tid >> 6;          // 0..3
    float s = 0.f;
    #pragma unroll
    for (int i=0;i<32;i++) s += bf2f(ltile[(rh*32 + i)*64 + col]);
    atomicAdd(&vs[(b*HEADS + hh)*HD + col], s);
  }
}

// ---------------- flash attention: 32x32 MFMA, 3-deep LDS pipeline, counted vmcnt ----------------
__global__ __launch_bounds__(256,3) void attn_kernel(
    const short* __restrict__ Q, const short* __restrict__ K,
    const short* __restrict__ Vt,
    short* __restrict__ po, float* __restrict__ pml) {
  const int nqt = TSEQ/128;            // 16
  int bid = blockIdx.x;
  int ks_id = bid % KSPLIT;
  int r = bid / KSPLIT;
  int qt = r % nqt;
  int bh = r / nqt;

  int tid = threadIdx.x;
  int w = tid >> 6, lane = tid & 63;
  int q5 = lane & 31, hi = lane >> 5;
  int qrow = qt*128 + w*32 + q5;

  // triple-buffered K and Vt tiles: 64 rows x 128B each, XOR-swizzled 16B chunks
  __shared__ __align__(16) char kbuf[3][8192];
  __shared__ __align__(16) char vbuf[3][8192];

  const short* Qp  = Q  + (size_t)bh*TSEQ*HD;
  const short* Kp  = K  + (size_t)bh*TSEQ*HD;
  const short* Vtp = Vt + (size_t)bh*HD*TSEQ;

  bf16x8 qf[4];
  #pragma unroll
  for (int c=0;c<4;c++)
    qf[c] = *(const bf16x8*)&Qp[(size_t)qrow*HD + c*16 + hi*8];

  const int ksoff = ks_id*(TSEQ/KSPLIT);   // 1024-key slice

  // per wave: 4 gload_lds per stage (2 K + 2 V)
  auto stage = [&](int buf, int kt) {
    int kb = ksoff + kt*KVBLK;
    #pragma unroll
    for (int i=0;i<2;i++) {
      int l0 = i*256 + w*64;
      int l  = l0 + lane;
      int rr = l >> 3, cc = l & 7;
      int sk = cc ^ (rr & 7);
      __builtin_amdgcn_global_load_lds(
        (const __attribute__((address_space(1))) unsigned int*)(Kp + (size_t)(kb + rr)*HD + sk*8),
        (__attribute__((address_space(3))) unsigned int*)(kbuf[buf] + l0*16),
        16, 0, 0);
      __builtin_amdgcn_global_load_lds(
        (const __attribute__((address_space(1))) unsigned int*)(Vtp + (size_t)rr*TSEQ + kb + sk*8),
        (__attribute__((address_space(3))) unsigned int*)(vbuf[buf] + l0*16),
        16, 0, 0);
    }
  };

  f32x16 o0 = (f32x16)0.f, o1 = (f32x16)0.f;
  float psum0 = 0.f, psum1 = 0.f;
  const int rx = q5 & 7;

  stage(0, 0);
  stage(1, 1);
  asm volatile("s_waitcnt vmcnt(4)" ::: "memory");   // tile 0 landed; tile 1 in flight
  __builtin_amdgcn_s_barrier();

  const int NT = TSEQ/KSPLIT/KVBLK;   // 16
  for (int kt = 0; kt < NT; kt++) {
    int cur = kt % 3;
    if (kt + 2 < NT) stage((kt + 2) % 3, kt + 2);   // issue early: 2 iterations of cover

    #pragma unroll
    for (int t=0;t<2;t++) {
      bf16x8 kf[4];
      #pragma unroll
      for (int c=0;c<4;c++)
        kf[c] = *(const bf16x8*)(kbuf[cur] + (t*32+q5)*128 + (((c*2+hi) ^ rx)*16));

      f32x16 st = (f32x16)0.f;
      __builtin_amdgcn_s_setprio(1);
      #pragma unroll
      for (int c=0;c<4;c++)
        st = __builtin_amdgcn_mfma_f32_32x32x16_bf16(kf[c], qf[c], st, 0, 0, 0);
      __builtin_amdgcn_s_setprio(0);

      bf16x8 vf0[2], vf1[2];
      #pragma unroll
      for (int ks2=0;ks2<2;ks2++) {
        int kc = ((t*4 + ks2*2 + hi) ^ rx)*16;
        vf0[ks2] = *(const bf16x8*)(vbuf[cur] + q5*128 + kc);
        vf1[ks2] = *(const bf16x8*)(vbuf[cur] + (q5+32)*128 + kc);
      }

      // Q pre-scaled by 0.125*log2e; the -8 bias cancels in O/L -> bare exp2
      #pragma unroll
      for (int i=0;i<16;i+=2) {
        st[i]   = __builtin_amdgcn_exp2f(st[i]);
        st[i+1] = __builtin_amdgcn_exp2f(st[i+1]);
        psum0 += st[i];
        psum1 += st[i+1];
      }
      unsigned pw[4][2];
      #pragma unroll
      for (int a=0;a<4;a++)
        #pragma unroll
        for (int p=0;p<2;p++) {
          union { __hip_bfloat162 h; unsigned u; } cvp;
          cvp.h = __float22bfloat162_rn(float2{st[a*4+2*p], st[a*4+2*p+1]});
          pw[a][p] = cvp.u;
        }
      #pragma unroll
      for (int ks2=0;ks2<2;ks2++) {
        uint32x2 s0 = __builtin_amdgcn_permlane32_swap(pw[2*ks2][0],   pw[2*ks2][0],   false, false);
        uint32x2 s1 = __builtin_amdgcn_permlane32_swap(pw[2*ks2][1],   pw[2*ks2][1],   false, false);
        uint32x2 s2 = __builtin_amdgcn_permlane32_swap(pw[2*ks2+1][0], pw[2*ks2+1][0], false, false);
        uint32x2 s3 = __builtin_amdgcn_permlane32_swap(pw[2*ks2+1][1], pw[2*ks2+1][1], false, false);
        union { unsigned u[4]; bf16x8 v; } bw;
        bw.u[0] = s0[0];
        bw.u[1] = s1[0];
        bw.u[2] = s2[1];
        bw.u[3] = s3[1];
        __builtin_amdgcn_s_setprio(1);
        o0 = __builtin_amdgcn_mfma_f32_32x32x16_bf16(vf0[ks2], bw.v, o0, 0, 0, 0);
        o1 = __builtin_amdgcn_mfma_f32_32x32x16_bf16(vf1[ks2], bw.v, o1, 0, 0, 0);
        __builtin_amdgcn_s_setprio(0);
      }
    }

    // counted drain: tile kt+1 must have landed; tile kt+2 stays in flight (never vmcnt(0) mid-loop)
    if (kt + 2 < NT) {
      asm volatile("s_waitcnt vmcnt(4)" ::: "memory");
      __builtin_amdgcn_s_barrier();
    } else if (kt + 1 < NT) {
      asm volatile("s_waitcnt vmcnt(0)" ::: "memory");
      __builtin_amdgcn_s_barrier();
    }
  }

  float psum = psum0 + psum1;
  float ltot = psum + __shfl_xor(psum, 32);
  size_t gq = (size_t)bh*TSEQ + qrow;
  if (!hi) pml[gq*KSPLIT + ks_id] = ltot;

  #pragma unroll
  for (int rg=0; rg<4; rg++) {
    bf16x4 pk0, pk1;
    #pragma unroll
    for (int rj=0;rj<4;rj++) { pk0[rj] = f2bf(o0[rg*4+rj]); pk1[rj] = f2bf(o1[rg*4+rj]); }
    int d0 = rg*8 + hi*4;
    *(bf16x4*)&po[(gq*KSPLIT + ks_id)*HD + d0]      = pk0;
    *(bf16x4*)&po[(gq*KSPLIT + ks_id)*HD + 32 + d0] = pk1;
  }
}

// ---------------- combine split-K partials + shaped epilogue (wide loads) ----------------
__global__ __launch_bounds__(256) void combine_kernel(
    const short* __restrict__ po, const float* __restrict__ pml,
    const short* __restrict__ V, const float* __restrict__ vs,
    const float* __restrict__ alpha, const float* __restrict__ beta,
    const float* __restrict__ gamma, const float* __restrict__ Cc,
    float* __restrict__ out) {
  int t = threadIdx.x;
  size_t gq = (size_t)blockIdx.x*32 + (t >> 3);   // 32 q-rows per block
  int d0 = (t & 7)*8;                              // 8 dims per lane
  int bh = (int)(gq >> 11), q = (int)(gq & (TSEQ-1));
  int b = bh / HEADS, h = bh % HEADS;

  float L = 0.f;
  float acc[8] = {0,0,0,0,0,0,0,0};
  #pragma unroll
  for (int i=0;i<KSPLIT;i++) {
    L += pml[gq*KSPLIT + i];
    bf16x8 p8 = *(const bf16x8*)&po[(gq*KSPLIT + i)*HD + d0];
    #pragma unroll
    for (int j=0;j<8;j++) acc[j] += bf2f(p8[j]);
  }
  float inv = 1.f / L;
  float al = alpha[h], be = beta[h], gc = gamma[h]*Cc[h];
  bf16x8 v8 = *(const bf16x8*)&V[((size_t)bh*TSEQ + q)*HD + d0];
  f32x4 vs0 = *(const f32x4*)&vs[bh*HD + d0];
  f32x4 vs1 = *(const f32x4*)&vs[bh*HD + d0 + 4];
  f32x4 r0, r1;
  #pragma unroll
  for (int j=0;j<4;j++) {
    r0[j] = al*bf2f(v8[j])   + be*acc[j]*inv   - gc*vs0[j];
    r1[j] = al*bf2f(v8[j+4]) + be*acc[j+4]*inv - gc*vs1[j];
  }
  float* op = &out[((size_t)b*TSEQ + q)*DMODEL + h*HD + d0];
  *(f32x4*)op = r0;
  *(f32x4*)(op+4) = r1;
}

extern "C" void kernel_launch(void* const* d_in, const int* in_sizes, int n_in,
                              void* d_out, int out_size, void* d_ws, size_t ws_size,
                              hipStream_t stream) {
  const float* x     = (const float*)d_in[0];
  const float* Wq    = (const float*)d_in[1];
  const float* bq    = (const float*)d_in[2];
  const float* Wk    = (const float*)d_in[3];
  const float* bk    = (const float*)d_in[4];
  const float* Wv    = (const float*)d_in[5];
  const float* bv    = (const float*)d_in[6];
  const float* alpha = (const float*)d_in[7];
  const float* beta  = (const float*)d_in[8];
  const float* gamma = (const float*)d_in[9];
  const float* Cc    = (const float*)d_in[10];
  float* out = (float*)d_out;

  char* ws = (char*)d_ws;
  size_t off = 0;
  auto alloc = [&](size_t bytes) -> void* {
    void* p = ws + off; off += (bytes + 255) & ~(size_t)255; return p;
  };
  short* Xb = (short*)alloc((size_t)NTOK*DMODEL*2);
  short* Wc = (short*)alloc((size_t)NQKV*DMODEL*2);
  float* bc = (float*)alloc((size_t)NQKV*4);
  short* Q  = (short*)alloc((size_t)BATCH*HEADS*TSEQ*HD*2);
  short* K  = (short*)alloc((size_t)BATCH*HEADS*TSEQ*HD*2);
  short* V  = (short*)alloc((size_t)BATCH*HEADS*TSEQ*HD*2);
  short* Vt = (short*)alloc((size_t)BATCH*HEADS*TSEQ*HD*2);
  float* vs = (float*)alloc((size_t)BATCH*HEADS*HD*4);
  short* po  = (short*)alloc((size_t)BATCH*HEADS*TSEQ*KSPLIT*HD*2);   // 12.6 MB
  float* pml = (float*)alloc((size_t)BATCH*HEADS*TSEQ*KSPLIT*4);      // 0.4 MB

  hipMemsetAsync(vs, 0, (size_t)BATCH*HEADS*HD*4, stream);
  cvt_kernel<<<2048, 256, 0, stream>>>(x, Wq, Wk, Wv, bq, bk, bv, Xb, Wc, bc);
  qkv_gemm<<<(NTOK/128)*(NQKV/64), 256, 0, stream>>>(Xb, Wc, bc, Q, K, V, Vt, vs);
  attn_kernel<<<BATCH*HEADS*(TSEQ/128)*KSPLIT, 256, 0, stream>>>(Q, K, Vt, po, pml);
  combine_kernel<<<BATCH*HEADS*TSEQ/32, 256, 0, stream>>>(po, pml, V, vs, alpha, beta, gamma, Cc, out);
}

// Round 16
// 85.134 us; speedup vs baseline: 1.2728x; 1.0265x over previous
//
#include <hip/hip_runtime.h>
#include <hip/hip_bf16.h>

#define HEADS 12
#define HD 64
#define DMODEL 768
#define TSEQ 2048
#define BATCH 2
#define NTOK (BATCH*TSEQ)   // 4096
#define NQKV (3*DMODEL)     // 2304
#define KSPLIT 4
#define BK 64
#define KVBLK 64
#define QSCALE 0.1803368801f   // 0.125 * log2(e); folded into Q so attn exp is bare exp2

typedef __attribute__((ext_vector_type(8))) short bf16x8;
typedef __attribute__((ext_vector_type(4))) short bf16x4;
typedef __attribute__((ext_vector_type(4))) float f32x4;
typedef __attribute__((ext_vector_type(16))) float f32x16;
typedef __attribute__((ext_vector_type(2))) unsigned uint32x2;

static __device__ inline float bf2f(short s) {
  union { float f; unsigned u; } cv; cv.u = ((unsigned)(unsigned short)s) << 16; return cv.f;
}
static __device__ inline short f2bf(float f) {
  union { float f; unsigned u; } cv; cv.f = f;
  unsigned u = cv.u;
  unsigned r = u + 0x7FFF + ((u >> 16) & 1);   // RNE
  return (short)(r >> 16);
}

// ---------------- conversion / packing (vectorized) + vs zeroing ----------------
__global__ void cvt_kernel(const float* __restrict__ x,
                           const float* __restrict__ Wq, const float* __restrict__ Wk,
                           const float* __restrict__ Wv,
                           const float* __restrict__ bq, const float* __restrict__ bk,
                           const float* __restrict__ bv,
                           short* __restrict__ Xb, short* __restrict__ Wc,
                           float* __restrict__ bc, float* __restrict__ vs) {
  int g = blockIdx.x*blockDim.x + threadIdx.x;
  if (g < BATCH*HEADS*HD) vs[g] = 0.f;    // zero colsum accumulator (replaces memset)
  const int NX4 = NTOK*DMODEL/4;          // 786432
  const int WSZ = DMODEL*DMODEL;          // 589824
  const int NW4 = 3*WSZ/4;                // 442368
  const int total = NX4 + NW4 + NQKV;
  for (int i = g; i < total; i += gridDim.x*blockDim.x) {
    if (i < NX4) {
      f32x4 v = *(const f32x4*)&x[i*4];
      bf16x4 o;
      #pragma unroll
      for (int j=0;j<4;j++) o[j] = f2bf(v[j]);
      *(bf16x4*)&Xb[i*4] = o;
    } else if (i < NX4 + NW4) {
      int j = (i - NX4)*4;
      const float* src = (j < WSZ) ? &Wq[j] : (j < 2*WSZ) ? &Wk[j - WSZ] : &Wv[j - 2*WSZ];
      f32x4 v = *(const f32x4*)src;
      bf16x4 o;
      #pragma unroll
      for (int jj=0;jj<4;jj++) o[jj] = f2bf(v[jj]);
      *(bf16x4*)&Wc[j] = o;
    } else {
      int o = i - NX4 - NW4;
      bc[o] = (o < DMODEL) ? bq[o] : (o < 2*DMODEL) ? bk[o - DMODEL] : bv[o - 2*DMODEL];
    }
  }
}

// ---------------- fused QKV GEMM, 128x64 tile (1 head/block), LDS dbuf + gload_lds + swizzle ----------------
__global__ __launch_bounds__(256,3) void qkv_gemm(const short* __restrict__ Xb,
                                                  const short* __restrict__ Wc,
                                                  const float* __restrict__ bc,
                                                  short* __restrict__ Q, short* __restrict__ K,
                                                  short* __restrict__ V, short* __restrict__ Vt,
                                                  float* __restrict__ vs) {
  __shared__ __align__(16) char lds[49152];   // A0(16K)|B0(8K)|A1(16K)|B1(8K)
  const int nbn = NQKV/64;            // 36
  // XCD-aware bijective swizzle: 1152 = 8 x 144
  int swzb = ((blockIdx.x & 7) * 144) + (blockIdx.x >> 3);
  int bm = swzb / nbn, bn = swzb % nbn;
  int trow = bm*128, tcol = bn*64;
  int tid = threadIdx.x;
  int w = tid >> 6, l = tid & 63;
  int wr = w >> 1, wc = w & 1;
  int lr = l & 15, lg = l >> 4;

  int rbase = tid >> 3;                 // 0..31
  int csw   = (tid & 7) ^ (rbase & 7);  // inverse-swizzled 16B chunk within row
  const short* pA = Xb + (size_t)(trow + rbase)*DMODEL + csw*8;
  const short* pB = Wc + (size_t)(tcol + rbase)*DMODEL + csw*8;

  unsigned aoff[4][2], boff[2][2];
  #pragma unroll
  for (int m=0;m<4;m++)
    #pragma unroll
    for (int kc2=0;kc2<2;kc2++) {
      int rowa = wr*64 + m*16 + lr;
      aoff[m][kc2] = rowa*128 + (((kc2*4+lg) ^ (rowa&7))*16);
    }
  #pragma unroll
  for (int n=0;n<2;n++)
    #pragma unroll
    for (int kc2=0;kc2<2;kc2++) {
      int rowb = wc*32 + n*16 + lr;
      boff[n][kc2] = rowb*128 + (((kc2*4+lg) ^ (rowb&7))*16);
    }

  f32x4 acc[4][2];
  #pragma unroll
  for (int m=0;m<4;m++)
    #pragma unroll
    for (int n=0;n<2;n++) acc[m][n] = (f32x4)0.f;

  auto stage = [&](int buf, int ks) {
    int k0 = ks*BK;
    unsigned base = (unsigned)buf*24576u;
    #pragma unroll
    for (int i=0;i<4;i++)
      __builtin_amdgcn_global_load_lds(
        (const __attribute__((address_space(1))) unsigned int*)(pA + k0 + i*(32*DMODEL)),
        (__attribute__((address_space(3))) unsigned int*)(lds + base + (i*256 + w*64)*16),
        16, 0, 0);
    #pragma unroll
    for (int i=0;i<2;i++)
      __builtin_amdgcn_global_load_lds(
        (const __attribute__((address_space(1))) unsigned int*)(pB + k0 + i*(32*DMODEL)),
        (__attribute__((address_space(3))) unsigned int*)(lds + base + 16384 + (i*256 + w*64)*16),
        16, 0, 0);
  };

  stage(0, 0);
  asm volatile("s_waitcnt vmcnt(0)" ::: "memory");
  __syncthreads();

  const int NKS = DMODEL/BK;   // 12
  for (int ks = 0; ks < NKS; ks++) {
    int cur = ks & 1;
    if (ks + 1 < NKS) stage(cur ^ 1, ks + 1);
    unsigned abase = (unsigned)cur*24576u, bbase = abase + 16384u;
    bf16x8 af[4][2], bfr[2][2];
    #pragma unroll
    for (int m=0;m<4;m++)
      #pragma unroll
      for (int kc2=0;kc2<2;kc2++)
        af[m][kc2] = *(const bf16x8*)(lds + abase + aoff[m][kc2]);
    #pragma unroll
    for (int n=0;n<2;n++)
      #pragma unroll
      for (int kc2=0;kc2<2;kc2++)
        bfr[n][kc2] = *(const bf16x8*)(lds + bbase + boff[n][kc2]);
    __builtin_amdgcn_s_setprio(1);
    #pragma unroll
    for (int m=0;m<4;m++)
      #pragma unroll
      for (int n=0;n<2;n++)
        #pragma unroll
        for (int kc2=0;kc2<2;kc2++)
          acc[m][n] = __builtin_amdgcn_mfma_f32_16x16x32_bf16(af[m][kc2], bfr[n][kc2], acc[m][n], 0, 0, 0);
    __builtin_amdgcn_s_setprio(0);
    __syncthreads();
  }

  // ---- epilogue: stage 128x64 bf16 tile in LDS, coalesced stores ----
  short* ltile = (short*)lds;
  int sel = tcol / DMODEL;            // 0=Q 1=K 2=V
  int hh  = (tcol % DMODEL) >> 6;     // single head
  float qsc = (sel == 0) ? QSCALE : 1.f;
  float bcv[2];
  #pragma unroll
  for (int n=0;n<2;n++) bcv[n] = bc[tcol + wc*32 + n*16 + lr];
  #pragma unroll
  for (int m=0;m<4;m++)
    #pragma unroll
    for (int n=0;n<2;n++)
      #pragma unroll
      for (int j=0;j<4;j++)
        ltile[(wr*64 + m*16 + lg*4 + j)*64 + wc*32 + n*16 + lr] = f2bf((acc[m][n][j] + bcv[n]) * qsc);
  __syncthreads();

  short* dstQKV = (sel == 0) ? Q : (sel == 1) ? K : V;
  int b = trow >> 11;
  #pragma unroll
  for (int rr=0; rr<4; rr++) {
    int idx = rr*256 + tid;           // 1024 chunks of 16B
    int r2 = idx >> 3, c2 = idx & 7;
    int tt = (trow + r2) & (TSEQ-1);
    bf16x8 val = *(const bf16x8*)&ltile[r2*64 + c2*8];
    *(bf16x8*)&dstQKV[((size_t)(b*HEADS + hh)*TSEQ + tt)*HD + c2*8] = val;
  }
  if (sel == 2) {
    #pragma unroll
    for (int rr=0; rr<4; rr++) {
      int idx = rr*256 + tid;         // 64 cols x 16 t-chunks
      int col = idx >> 4, tc8 = idx & 15;
      int tt0 = (trow + tc8*8) & (TSEQ-1);
      bf16x8 v;
      #pragma unroll
      for (int j=0;j<8;j++) v[j] = ltile[(tc8*8 + j)*64 + col];
      *(bf16x8*)&Vt[((size_t)(b*HEADS + hh)*HD + col)*TSEQ + tt0] = v;
    }
    // fused V column-sum: each thread sums a quarter-column, atomic into vs
    int col = tid & 63;
    int rh  = tid >> 6;          // 0..3
    float s = 0.f;
    #pragma unroll
    for (int i=0;i<32;i++) s += bf2f(ltile[(rh*32 + i)*64 + col]);
    atomicAdd(&vs[(b*HEADS + hh)*HD + col], s);
  }
}

// ---------------- flash attention: 32x32 MFMA, 2-deep LDS pipeline, 4 waves/SIMD target ----------------
__global__ __launch_bounds__(256,4) void attn_kernel(
    const short* __restrict__ Q, const short* __restrict__ K,
    const short* __restrict__ Vt,
    short* __restrict__ po, float* __restrict__ pml) {
  const int nqt = TSEQ/128;            // 16
  int bid = blockIdx.x;
  int ks_id = bid % KSPLIT;
  int r = bid / KSPLIT;
  int qt = r % nqt;
  int bh = r / nqt;

  int tid = threadIdx.x;
  int w = tid >> 6, lane = tid & 63;
  int q5 = lane & 31, hi = lane >> 5;
  int qrow = qt*128 + w*32 + q5;

  // double-buffered K and Vt tiles: 64 rows x 128B each, XOR-swizzled 16B chunks
  __shared__ __align__(16) char kbuf[2][8192];
  __shared__ __align__(16) char vbuf[2][8192];

  const short* Qp  = Q  + (size_t)bh*TSEQ*HD;
  const short* Kp  = K  + (size_t)bh*TSEQ*HD;
  const short* Vtp = Vt + (size_t)bh*HD*TSEQ;

  bf16x8 qf[4];
  #pragma unroll
  for (int c=0;c<4;c++)
    qf[c] = *(const bf16x8*)&Qp[(size_t)qrow*HD + c*16 + hi*8];

  const int ksoff = ks_id*(TSEQ/KSPLIT);   // 512-key slice

  auto stage = [&](int buf, int kt) {
    int kb = ksoff + kt*KVBLK;
    #pragma unroll
    for (int i=0;i<2;i++) {
      int l0 = i*256 + w*64;
      int l  = l0 + lane;
      int rr = l >> 3, cc = l & 7;
      int sk = cc ^ (rr & 7);
      __builtin_amdgcn_global_load_lds(
        (const __attribute__((address_space(1))) unsigned int*)(Kp + (size_t)(kb + rr)*HD + sk*8),
        (__attribute__((address_space(3))) unsigned int*)(kbuf[buf] + l0*16),
        16, 0, 0);
      __builtin_amdgcn_global_load_lds(
        (const __attribute__((address_space(1))) unsigned int*)(Vtp + (size_t)rr*TSEQ + kb + sk*8),
        (__attribute__((address_space(3))) unsigned int*)(vbuf[buf] + l0*16),
        16, 0, 0);
    }
  };

  f32x16 o0 = (f32x16)0.f, o1 = (f32x16)0.f;
  float psum0 = 0.f, psum1 = 0.f;
  const int rx = q5 & 7;

  stage(0, 0);
  asm volatile("s_waitcnt vmcnt(0)" ::: "memory");
  __builtin_amdgcn_s_barrier();

  const int NT = TSEQ/KSPLIT/KVBLK;   // 8
  for (int kt = 0; kt < NT; kt++) {
    int cur = kt & 1;
    if (kt + 1 < NT) stage(cur ^ 1, kt + 1);

    #pragma unroll
    for (int t=0;t<2;t++) {
      bf16x8 kf[4];
      #pragma unroll
      for (int c=0;c<4;c++)
        kf[c] = *(const bf16x8*)(kbuf[cur] + (t*32+q5)*128 + (((c*2+hi) ^ rx)*16));

      f32x16 st = (f32x16)0.f;
      __builtin_amdgcn_s_setprio(1);
      #pragma unroll
      for (int c=0;c<4;c++)
        st = __builtin_amdgcn_mfma_f32_32x32x16_bf16(kf[c], qf[c], st, 0, 0, 0);
      __builtin_amdgcn_s_setprio(0);

      // Q pre-scaled by 0.125*log2e; the -8 bias cancels in O/L -> bare exp2
      #pragma unroll
      for (int i=0;i<16;i+=2) {
        st[i]   = __builtin_amdgcn_exp2f(st[i]);
        st[i+1] = __builtin_amdgcn_exp2f(st[i+1]);
        psum0 += st[i];
        psum1 += st[i+1];
      }
      unsigned pw[4][2];
      #pragma unroll
      for (int a=0;a<4;a++)
        #pragma unroll
        for (int p=0;p<2;p++) {
          union { __hip_bfloat162 h; unsigned u; } cvp;
          cvp.h = __float22bfloat162_rn(float2{st[a*4+2*p], st[a*4+2*p+1]});
          pw[a][p] = cvp.u;
        }
      #pragma unroll
      for (int ks2=0;ks2<2;ks2++) {
        uint32x2 s0 = __builtin_amdgcn_permlane32_swap(pw[2*ks2][0],   pw[2*ks2][0],   false, false);
        uint32x2 s1 = __builtin_amdgcn_permlane32_swap(pw[2*ks2][1],   pw[2*ks2][1],   false, false);
        uint32x2 s2 = __builtin_amdgcn_permlane32_swap(pw[2*ks2+1][0], pw[2*ks2+1][0], false, false);
        uint32x2 s3 = __builtin_amdgcn_permlane32_swap(pw[2*ks2+1][1], pw[2*ks2+1][1], false, false);
        union { unsigned u[4]; bf16x8 v; } bw;
        bw.u[0] = s0[0];
        bw.u[1] = s1[0];
        bw.u[2] = s2[1];
        bw.u[3] = s3[1];
        // Vt fragments loaded at use (shorter live range; TLP hides LDS latency)
        int kc = ((t*4 + ks2*2 + hi) ^ rx)*16;
        bf16x8 vf0 = *(const bf16x8*)(vbuf[cur] + q5*128 + kc);
        bf16x8 vf1 = *(const bf16x8*)(vbuf[cur] + (q5+32)*128 + kc);
        __builtin_amdgcn_s_setprio(1);
        o0 = __builtin_amdgcn_mfma_f32_32x32x16_bf16(vf0, bw.v, o0, 0, 0, 0);
        o1 = __builtin_amdgcn_mfma_f32_32x32x16_bf16(vf1, bw.v, o1, 0, 0, 0);
        __builtin_amdgcn_s_setprio(0);
      }
    }

    if (kt + 1 < NT) {
      asm volatile("s_waitcnt vmcnt(0)" ::: "memory");
      __builtin_amdgcn_s_barrier();
    }
  }

  float psum = psum0 + psum1;
  float ltot = psum + __shfl_xor(psum, 32);
  size_t gq = (size_t)bh*TSEQ + qrow;
  if (!hi) pml[gq*KSPLIT + ks_id] = ltot;

  #pragma unroll
  for (int rg=0; rg<4; rg++) {
    bf16x4 pk0, pk1;
    #pragma unroll
    for (int rj=0;rj<4;rj++) { pk0[rj] = f2bf(o0[rg*4+rj]); pk1[rj] = f2bf(o1[rg*4+rj]); }
    int d0 = rg*8 + hi*4;
    *(bf16x4*)&po[(gq*KSPLIT + ks_id)*HD + d0]      = pk0;
    *(bf16x4*)&po[(gq*KSPLIT + ks_id)*HD + 32 + d0] = pk1;
  }
}

// ---------------- combine split-K partials + shaped epilogue (wide loads) ----------------
__global__ __launch_bounds__(256) void combine_kernel(
    const short* __restrict__ po, const float* __restrict__ pml,
    const short* __restrict__ V, const float* __restrict__ vs,
    const float* __restrict__ alpha, const float* __restrict__ beta,
    const float* __restrict__ gamma, const float* __restrict__ Cc,
    float* __restrict__ out) {
  int t = threadIdx.x;
  size_t gq = (size_t)blockIdx.x*32 + (t >> 3);   // 32 q-rows per block
  int d0 = (t & 7)*8;                              // 8 dims per lane
  int bh = (int)(gq >> 11), q = (int)(gq & (TSEQ-1));
  int b = bh / HEADS, h = bh % HEADS;

  float L = 0.f;
  float acc[8] = {0,0,0,0,0,0,0,0};
  #pragma unroll
  for (int i=0;i<KSPLIT;i++) {
    L += pml[gq*KSPLIT + i];
    bf16x8 p8 = *(const bf16x8*)&po[(gq*KSPLIT + i)*HD + d0];
    #pragma unroll
    for (int j=0;j<8;j++) acc[j] += bf2f(p8[j]);
  }
  float inv = 1.f / L;
  float al = alpha[h], be = beta[h], gc = gamma[h]*Cc[h];
  bf16x8 v8 = *(const bf16x8*)&V[((size_t)bh*TSEQ + q)*HD + d0];
  f32x4 vs0 = *(const f32x4*)&vs[bh*HD + d0];
  f32x4 vs1 = *(const f32x4*)&vs[bh*HD + d0 + 4];
  f32x4 r0, r1;
  #pragma unroll
  for (int j=0;j<4;j++) {
    r0[j] = al*bf2f(v8[j])   + be*acc[j]*inv   - gc*vs0[j];
    r1[j] = al*bf2f(v8[j+4]) + be*acc[j+4]*inv - gc*vs1[j];
  }
  float* op = &out[((size_t)b*TSEQ + q)*DMODEL + h*HD + d0];
  *(f32x4*)op = r0;
  *(f32x4*)(op+4) = r1;
}

extern "C" void kernel_launch(void* const* d_in, const int* in_sizes, int n_in,
                              void* d_out, int out_size, void* d_ws, size_t ws_size,
                              hipStream_t stream) {
  const float* x     = (const float*)d_in[0];
  const float* Wq    = (const float*)d_in[1];
  const float* bq    = (const float*)d_in[2];
  const float* Wk    = (const float*)d_in[3];
  const float* bk    = (const float*)d_in[4];
  const float* Wv    = (const float*)d_in[5];
  const float* bv    = (const float*)d_in[6];
  const float* alpha = (const float*)d_in[7];
  const float* beta  = (const float*)d_in[8];
  const float* gamma = (const float*)d_in[9];
  const float* Cc    = (const float*)d_in[10];
  float* out = (float*)d_out;

  char* ws = (char*)d_ws;
  size_t off = 0;
  auto alloc = [&](size_t bytes) -> void* {
    void* p = ws + off; off += (bytes + 255) & ~(size_t)255; return p;
  };
  short* Xb = (short*)alloc((size_t)NTOK*DMODEL*2);
  short* Wc = (short*)alloc((size_t)NQKV*DMODEL*2);
  float* bc = (float*)alloc((size_t)NQKV*4);
  short* Q  = (short*)alloc((size_t)BATCH*HEADS*TSEQ*HD*2);
  short* K  = (short*)alloc((size_t)BATCH*HEADS*TSEQ*HD*2);
  short* V  = (short*)alloc((size_t)BATCH*HEADS*TSEQ*HD*2);
  short* Vt = (short*)alloc((size_t)BATCH*HEADS*TSEQ*HD*2);
  float* vs = (float*)alloc((size_t)BATCH*HEADS*HD*4);
  short* po  = (short*)alloc((size_t)BATCH*HEADS*TSEQ*KSPLIT*HD*2);   // 25.2 MB
  float* pml = (float*)alloc((size_t)BATCH*HEADS*TSEQ*KSPLIT*4);      // 0.8 MB

  cvt_kernel<<<2048, 256, 0, stream>>>(x, Wq, Wk, Wv, bq, bk, bv, Xb, Wc, bc, vs);
  qkv_gemm<<<(NTOK/128)*(NQKV/64), 256, 0, stream>>>(Xb, Wc, bc, Q, K, V, Vt, vs);
  attn_kernel<<<BATCH*HEADS*(TSEQ/128)*KSPLIT, 256, 0, stream>>>(Q, K, Vt, po, pml);
  combine_kernel<<<BATCH*HEADS*TSEQ/32, 256, 0, stream>>>(po, pml, V, vs, alpha, beta, gamma, Cc, out);
}

// Round 17
// 82.745 us; speedup vs baseline: 1.3096x; 1.0289x over previous
//
#include <hip/hip_runtime.h>
#include <hip/hip_bf16.h>

#define HEADS 12
#define HD 64
#define DMODEL 768
#define TSEQ 2048
#define BATCH 2
#define NTOK (BATCH*TSEQ)   // 4096
#define NQKV (3*DMODEL)     // 2304
#define KSPLIT 2
#define BK 64
#define KVBLK 64
#define QSCALE 0.1803368801f   // 0.125 * log2(e); folded into Q so attn exp is bare exp2

typedef __attribute__((ext_vector_type(8))) short bf16x8;
typedef __attribute__((ext_vector_type(4))) short bf16x4;
typedef __attribute__((ext_vector_type(4))) float f32x4;
typedef __attribute__((ext_vector_type(16))) float f32x16;
typedef __attribute__((ext_vector_type(2))) unsigned uint32x2;

static __device__ inline float bf2f(short s) {
  union { float f; unsigned u; } cv; cv.u = ((unsigned)(unsigned short)s) << 16; return cv.f;
}
static __device__ inline short f2bf(float f) {
  union { float f; unsigned u; } cv; cv.f = f;
  unsigned u = cv.u;
  unsigned r = u + 0x7FFF + ((u >> 16) & 1);   // RNE
  return (short)(r >> 16);
}

// ---------------- conversion / packing (vectorized) + vs zeroing ----------------
__global__ void cvt_kernel(const float* __restrict__ x,
                           const float* __restrict__ Wq, const float* __restrict__ Wk,
                           const float* __restrict__ Wv,
                           const float* __restrict__ bq, const float* __restrict__ bk,
                           const float* __restrict__ bv,
                           short* __restrict__ Xb, short* __restrict__ Wc,
                           float* __restrict__ bc, float* __restrict__ vs) {
  int g = blockIdx.x*blockDim.x + threadIdx.x;
  if (g < BATCH*HEADS*HD) vs[g] = 0.f;    // zero colsum accumulator (replaces memset)
  const int NX4 = NTOK*DMODEL/4;          // 786432
  const int WSZ = DMODEL*DMODEL;          // 589824
  const int NW4 = 3*WSZ/4;                // 442368
  const int total = NX4 + NW4 + NQKV;
  for (int i = g; i < total; i += gridDim.x*blockDim.x) {
    if (i < NX4) {
      f32x4 v = *(const f32x4*)&x[i*4];
      bf16x4 o;
      #pragma unroll
      for (int j=0;j<4;j++) o[j] = f2bf(v[j]);
      *(bf16x4*)&Xb[i*4] = o;
    } else if (i < NX4 + NW4) {
      int j = (i - NX4)*4;
      const float* src = (j < WSZ) ? &Wq[j] : (j < 2*WSZ) ? &Wk[j - WSZ] : &Wv[j - 2*WSZ];
      f32x4 v = *(const f32x4*)src;
      bf16x4 o;
      #pragma unroll
      for (int jj=0;jj<4;jj++) o[jj] = f2bf(v[jj]);
      *(bf16x4*)&Wc[j] = o;
    } else {
      int o = i - NX4 - NW4;
      bc[o] = (o < DMODEL) ? bq[o] : (o < 2*DMODEL) ? bk[o - DMODEL] : bv[o - 2*DMODEL];
    }
  }
}

// ---------------- fused QKV GEMM, 128x64 tile (1 head/block), LDS dbuf + gload_lds + swizzle ----------------
__global__ __launch_bounds__(256,3) void qkv_gemm(const short* __restrict__ Xb,
                                                  const short* __restrict__ Wc,
                                                  const float* __restrict__ bc,
                                                  short* __restrict__ Q, short* __restrict__ K,
                                                  short* __restrict__ V, short* __restrict__ Vt,
                                                  float* __restrict__ vs) {
  __shared__ __align__(16) char lds[49152];   // A0(16K)|B0(8K)|A1(16K)|B1(8K)
  const int nbn = NQKV/64;            // 36
  // XCD-aware bijective swizzle: 1152 = 8 x 144
  int swzb = ((blockIdx.x & 7) * 144) + (blockIdx.x >> 3);
  int bm = swzb / nbn, bn = swzb % nbn;
  int trow = bm*128, tcol = bn*64;
  int tid = threadIdx.x;
  int w = tid >> 6, l = tid & 63;
  int wr = w >> 1, wc = w & 1;
  int lr = l & 15, lg = l >> 4;

  int rbase = tid >> 3;                 // 0..31
  int csw   = (tid & 7) ^ (rbase & 7);  // inverse-swizzled 16B chunk within row
  const short* pA = Xb + (size_t)(trow + rbase)*DMODEL + csw*8;
  const short* pB = Wc + (size_t)(tcol + rbase)*DMODEL + csw*8;

  unsigned aoff[4][2], boff[2][2];
  #pragma unroll
  for (int m=0;m<4;m++)
    #pragma unroll
    for (int kc2=0;kc2<2;kc2++) {
      int rowa = wr*64 + m*16 + lr;
      aoff[m][kc2] = rowa*128 + (((kc2*4+lg) ^ (rowa&7))*16);
    }
  #pragma unroll
  for (int n=0;n<2;n++)
    #pragma unroll
    for (int kc2=0;kc2<2;kc2++) {
      int rowb = wc*32 + n*16 + lr;
      boff[n][kc2] = rowb*128 + (((kc2*4+lg) ^ (rowb&7))*16);
    }

  f32x4 acc[4][2];
  #pragma unroll
  for (int m=0;m<4;m++)
    #pragma unroll
    for (int n=0;n<2;n++) acc[m][n] = (f32x4)0.f;

  auto stage = [&](int buf, int ks) {
    int k0 = ks*BK;
    unsigned base = (unsigned)buf*24576u;
    #pragma unroll
    for (int i=0;i<4;i++)
      __builtin_amdgcn_global_load_lds(
        (const __attribute__((address_space(1))) unsigned int*)(pA + k0 + i*(32*DMODEL)),
        (__attribute__((address_space(3))) unsigned int*)(lds + base + (i*256 + w*64)*16),
        16, 0, 0);
    #pragma unroll
    for (int i=0;i<2;i++)
      __builtin_amdgcn_global_load_lds(
        (const __attribute__((address_space(1))) unsigned int*)(pB + k0 + i*(32*DMODEL)),
        (__attribute__((address_space(3))) unsigned int*)(lds + base + 16384 + (i*256 + w*64)*16),
        16, 0, 0);
  };

  stage(0, 0);
  asm volatile("s_waitcnt vmcnt(0)" ::: "memory");
  __syncthreads();

  const int NKS = DMODEL/BK;   // 12
  for (int ks = 0; ks < NKS; ks++) {
    int cur = ks & 1;
    if (ks + 1 < NKS) stage(cur ^ 1, ks + 1);
    unsigned abase = (unsigned)cur*24576u, bbase = abase + 16384u;
    bf16x8 af[4][2], bfr[2][2];
    #pragma unroll
    for (int m=0;m<4;m++)
      #pragma unroll
      for (int kc2=0;kc2<2;kc2++)
        af[m][kc2] = *(const bf16x8*)(lds + abase + aoff[m][kc2]);
    #pragma unroll
    for (int n=0;n<2;n++)
      #pragma unroll
      for (int kc2=0;kc2<2;kc2++)
        bfr[n][kc2] = *(const bf16x8*)(lds + bbase + boff[n][kc2]);
    __builtin_amdgcn_s_setprio(1);
    #pragma unroll
    for (int m=0;m<4;m++)
      #pragma unroll
      for (int n=0;n<2;n++)
        #pragma unroll
        for (int kc2=0;kc2<2;kc2++)
          acc[m][n] = __builtin_amdgcn_mfma_f32_16x16x32_bf16(af[m][kc2], bfr[n][kc2], acc[m][n], 0, 0, 0);
    __builtin_amdgcn_s_setprio(0);
    __syncthreads();
  }

  // ---- epilogue: stage 128x64 bf16 tile in LDS, coalesced stores ----
  short* ltile = (short*)lds;
  int sel = tcol / DMODEL;            // 0=Q 1=K 2=V
  int hh  = (tcol % DMODEL) >> 6;     // single head
  float qsc = (sel == 0) ? QSCALE : 1.f;
  float bcv[2];
  #pragma unroll
  for (int n=0;n<2;n++) bcv[n] = bc[tcol + wc*32 + n*16 + lr];
  #pragma unroll
  for (int m=0;m<4;m++)
    #pragma unroll
    for (int n=0;n<2;n++)
      #pragma unroll
      for (int j=0;j<4;j++)
        ltile[(wr*64 + m*16 + lg*4 + j)*64 + wc*32 + n*16 + lr] = f2bf((acc[m][n][j] + bcv[n]) * qsc);
  __syncthreads();

  short* dstQKV = (sel == 0) ? Q : (sel == 1) ? K : V;
  int b = trow >> 11;
  #pragma unroll
  for (int rr=0; rr<4; rr++) {
    int idx = rr*256 + tid;           // 1024 chunks of 16B
    int r2 = idx >> 3, c2 = idx & 7;
    int tt = (trow + r2) & (TSEQ-1);
    bf16x8 val = *(const bf16x8*)&ltile[r2*64 + c2*8];
    *(bf16x8*)&dstQKV[((size_t)(b*HEADS + hh)*TSEQ + tt)*HD + c2*8] = val;
  }
  if (sel == 2) {
    #pragma unroll
    for (int rr=0; rr<4; rr++) {
      int idx = rr*256 + tid;         // 64 cols x 16 t-chunks
      int col = idx >> 4, tc8 = idx & 15;
      int tt0 = (trow + tc8*8) & (TSEQ-1);
      bf16x8 v;
      #pragma unroll
      for (int j=0;j<8;j++) v[j] = ltile[(tc8*8 + j)*64 + col];
      *(bf16x8*)&Vt[((size_t)(b*HEADS + hh)*HD + col)*TSEQ + tt0] = v;
    }
    // fused V column-sum: each thread sums a quarter-column, atomic into vs
    int col = tid & 63;
    int rh  = tid >> 6;          // 0..3
    float s = 0.f;
    #pragma unroll
    for (int i=0;i<32;i++) s += bf2f(ltile[(rh*32 + i)*64 + col]);
    atomicAdd(&vs[(b*HEADS + hh)*HD + col], s);
  }
}

// ---------------- flash attention: 32x32 MFMA, 2-deep LDS pipeline ----------------
__global__ __launch_bounds__(256,4) void attn_kernel(
    const short* __restrict__ Q, const short* __restrict__ K,
    const short* __restrict__ Vt,
    short* __restrict__ po, float* __restrict__ pml) {
  const int nqt = TSEQ/128;            // 16
  int bid = blockIdx.x;
  int ks_id = bid % KSPLIT;
  int r = bid / KSPLIT;
  int qt = r % nqt;
  int bh = r / nqt;

  int tid = threadIdx.x;
  int w = tid >> 6, lane = tid & 63;
  int q5 = lane & 31, hi = lane >> 5;
  int qrow = qt*128 + w*32 + q5;

  // double-buffered K and Vt tiles: 64 rows x 128B each, XOR-swizzled 16B chunks
  __shared__ __align__(16) char kbuf[2][8192];
  __shared__ __align__(16) char vbuf[2][8192];

  const short* Qp  = Q  + (size_t)bh*TSEQ*HD;
  const short* Kp  = K  + (size_t)bh*TSEQ*HD;
  const short* Vtp = Vt + (size_t)bh*HD*TSEQ;

  bf16x8 qf[4];
  #pragma unroll
  for (int c=0;c<4;c++)
    qf[c] = *(const bf16x8*)&Qp[(size_t)qrow*HD + c*16 + hi*8];

  const int ksoff = ks_id*(TSEQ/KSPLIT);   // 1024-key slice

  auto stage = [&](int buf, int kt) {
    int kb = ksoff + kt*KVBLK;
    #pragma unroll
    for (int i=0;i<2;i++) {
      int l0 = i*256 + w*64;
      int l  = l0 + lane;
      int rr = l >> 3, cc = l & 7;
      int sk = cc ^ (rr & 7);
      __builtin_amdgcn_global_load_lds(
        (const __attribute__((address_space(1))) unsigned int*)(Kp + (size_t)(kb + rr)*HD + sk*8),
        (__attribute__((address_space(3))) unsigned int*)(kbuf[buf] + l0*16),
        16, 0, 0);
      __builtin_amdgcn_global_load_lds(
        (const __attribute__((address_space(1))) unsigned int*)(Vtp + (size_t)rr*TSEQ + kb + sk*8),
        (__attribute__((address_space(3))) unsigned int*)(vbuf[buf] + l0*16),
        16, 0, 0);
    }
  };

  f32x16 o0 = (f32x16)0.f, o1 = (f32x16)0.f;
  float psum0 = 0.f, psum1 = 0.f;
  const int rx = q5 & 7;

  stage(0, 0);
  asm volatile("s_waitcnt vmcnt(0)" ::: "memory");
  __builtin_amdgcn_s_barrier();

  const int NT = TSEQ/KSPLIT/KVBLK;   // 16
  for (int kt = 0; kt < NT; kt++) {
    int cur = kt & 1;
    if (kt + 1 < NT) stage(cur ^ 1, kt + 1);

    #pragma unroll
    for (int t=0;t<2;t++) {
      bf16x8 kf[4];
      #pragma unroll
      for (int c=0;c<4;c++)
        kf[c] = *(const bf16x8*)(kbuf[cur] + (t*32+q5)*128 + (((c*2+hi) ^ rx)*16));

      f32x16 st = (f32x16)0.f;
      __builtin_amdgcn_s_setprio(1);
      #pragma unroll
      for (int c=0;c<4;c++)
        st = __builtin_amdgcn_mfma_f32_32x32x16_bf16(kf[c], qf[c], st, 0, 0, 0);
      __builtin_amdgcn_s_setprio(0);

      // Q pre-scaled by 0.125*log2e; the -8 bias cancels in O/L -> bare exp2
      #pragma unroll
      for (int i=0;i<16;i+=2) {
        st[i]   = __builtin_amdgcn_exp2f(st[i]);
        st[i+1] = __builtin_amdgcn_exp2f(st[i+1]);
        psum0 += st[i];
        psum1 += st[i+1];
      }
      unsigned pw[4][2];
      #pragma unroll
      for (int a=0;a<4;a++)
        #pragma unroll
        for (int p=0;p<2;p++) {
          union { __hip_bfloat162 h; unsigned u; } cvp;
          cvp.h = __float22bfloat162_rn(float2{st[a*4+2*p], st[a*4+2*p+1]});
          pw[a][p] = cvp.u;
        }
      #pragma unroll
      for (int ks2=0;ks2<2;ks2++) {
        uint32x2 s0 = __builtin_amdgcn_permlane32_swap(pw[2*ks2][0],   pw[2*ks2][0],   false, false);
        uint32x2 s1 = __builtin_amdgcn_permlane32_swap(pw[2*ks2][1],   pw[2*ks2][1],   false, false);
        uint32x2 s2 = __builtin_amdgcn_permlane32_swap(pw[2*ks2+1][0], pw[2*ks2+1][0], false, false);
        uint32x2 s3 = __builtin_amdgcn_permlane32_swap(pw[2*ks2+1][1], pw[2*ks2+1][1], false, false);
        union { unsigned u[4]; bf16x8 v; } bw;
        bw.u[0] = s0[0];
        bw.u[1] = s1[0];
        bw.u[2] = s2[1];
        bw.u[3] = s3[1];
        // Vt fragments loaded at use (shorter live range; TLP hides LDS latency)
        int kc = ((t*4 + ks2*2 + hi) ^ rx)*16;
        bf16x8 vf0 = *(const bf16x8*)(vbuf[cur] + q5*128 + kc);
        bf16x8 vf1 = *(const bf16x8*)(vbuf[cur] + (q5+32)*128 + kc);
        __builtin_amdgcn_s_setprio(1);
        o0 = __builtin_amdgcn_mfma_f32_32x32x16_bf16(vf0, bw.v, o0, 0, 0, 0);
        o1 = __builtin_amdgcn_mfma_f32_32x32x16_bf16(vf1, bw.v, o1, 0, 0, 0);
        __builtin_amdgcn_s_setprio(0);
      }
    }

    if (kt + 1 < NT) {
      asm volatile("s_waitcnt vmcnt(0)" ::: "memory");
      __builtin_amdgcn_s_barrier();
    }
  }

  float psum = psum0 + psum1;
  float ltot = psum + __shfl_xor(psum, 32);
  size_t gq = (size_t)bh*TSEQ + qrow;
  if (!hi) pml[gq*KSPLIT + ks_id] = ltot;

  #pragma unroll
  for (int rg=0; rg<4; rg++) {
    bf16x4 pk0, pk1;
    #pragma unroll
    for (int rj=0;rj<4;rj++) { pk0[rj] = f2bf(o0[rg*4+rj]); pk1[rj] = f2bf(o1[rg*4+rj]); }
    int d0 = rg*8 + hi*4;
    *(bf16x4*)&po[(gq*KSPLIT + ks_id)*HD + d0]      = pk0;
    *(bf16x4*)&po[(gq*KSPLIT + ks_id)*HD + 32 + d0] = pk1;
  }
}

// ---------------- combine split-K partials + shaped epilogue (wide loads) ----------------
__global__ __launch_bounds__(256) void combine_kernel(
    const short* __restrict__ po, const float* __restrict__ pml,
    const short* __restrict__ V, const float* __restrict__ vs,
    const float* __restrict__ alpha, const float* __restrict__ beta,
    const float* __restrict__ gamma, const float* __restrict__ Cc,
    float* __restrict__ out) {
  int t = threadIdx.x;
  size_t gq = (size_t)blockIdx.x*32 + (t >> 3);   // 32 q-rows per block
  int d0 = (t & 7)*8;                              // 8 dims per lane
  int bh = (int)(gq >> 11), q = (int)(gq & (TSEQ-1));
  int b = bh / HEADS, h = bh % HEADS;

  float L = 0.f;
  float acc[8] = {0,0,0,0,0,0,0,0};
  #pragma unroll
  for (int i=0;i<KSPLIT;i++) {
    L += pml[gq*KSPLIT + i];
    bf16x8 p8 = *(const bf16x8*)&po[(gq*KSPLIT + i)*HD + d0];
    #pragma unroll
    for (int j=0;j<8;j++) acc[j] += bf2f(p8[j]);
  }
  float inv = 1.f / L;
  float al = alpha[h], be = beta[h], gc = gamma[h]*Cc[h];
  bf16x8 v8 = *(const bf16x8*)&V[((size_t)bh*TSEQ + q)*HD + d0];
  f32x4 vs0 = *(const f32x4*)&vs[bh*HD + d0];
  f32x4 vs1 = *(const f32x4*)&vs[bh*HD + d0 + 4];
  f32x4 r0, r1;
  #pragma unroll
  for (int j=0;j<4;j++) {
    r0[j] = al*bf2f(v8[j])   + be*acc[j]*inv   - gc*vs0[j];
    r1[j] = al*bf2f(v8[j+4]) + be*acc[j+4]*inv - gc*vs1[j];
  }
  float* op = &out[((size_t)b*TSEQ + q)*DMODEL + h*HD + d0];
  *(f32x4*)op = r0;
  *(f32x4*)(op+4) = r1;
}

extern "C" void kernel_launch(void* const* d_in, const int* in_sizes, int n_in,
                              void* d_out, int out_size, void* d_ws, size_t ws_size,
                              hipStream_t stream) {
  const float* x     = (const float*)d_in[0];
  const float* Wq    = (const float*)d_in[1];
  const float* bq    = (const float*)d_in[2];
  const float* Wk    = (const float*)d_in[3];
  const float* bk    = (const float*)d_in[4];
  const float* Wv    = (const float*)d_in[5];
  const float* bv    = (const float*)d_in[6];
  const float* alpha = (const float*)d_in[7];
  const float* beta  = (const float*)d_in[8];
  const float* gamma = (const float*)d_in[9];
  const float* Cc    = (const float*)d_in[10];
  float* out = (float*)d_out;

  char* ws = (char*)d_ws;
  size_t off = 0;
  auto alloc = [&](size_t bytes) -> void* {
    void* p = ws + off; off += (bytes + 255) & ~(size_t)255; return p;
  };
  short* Xb = (short*)alloc((size_t)NTOK*DMODEL*2);
  short* Wc = (short*)alloc((size_t)NQKV*DMODEL*2);
  float* bc = (float*)alloc((size_t)NQKV*4);
  short* Q  = (short*)alloc((size_t)BATCH*HEADS*TSEQ*HD*2);
  short* K  = (short*)alloc((size_t)BATCH*HEADS*TSEQ*HD*2);
  short* V  = (short*)alloc((size_t)BATCH*HEADS*TSEQ*HD*2);
  short* Vt = (short*)alloc((size_t)BATCH*HEADS*TSEQ*HD*2);
  float* vs = (float*)alloc((size_t)BATCH*HEADS*HD*4);
  short* po  = (short*)alloc((size_t)BATCH*HEADS*TSEQ*KSPLIT*HD*2);   // 12.6 MB
  float* pml = (float*)alloc((size_t)BATCH*HEADS*TSEQ*KSPLIT*4);      // 0.4 MB

  cvt_kernel<<<2048, 256, 0, stream>>>(x, Wq, Wk, Wv, bq, bk, bv, Xb, Wc, bc, vs);
  qkv_gemm<<<(NTOK/128)*(NQKV/64), 256, 0, stream>>>(Xb, Wc, bc, Q, K, V, Vt, vs);
  attn_kernel<<<BATCH*HEADS*(TSEQ/128)*KSPLIT, 256, 0, stream>>>(Q, K, Vt, po, pml);
  combine_kernel<<<BATCH*HEADS*TSEQ/32, 256, 0, stream>>>(po, pml, V, vs, alpha, beta, gamma, Cc, out);
}